// Round 1
// baseline (2569.288 us; speedup 1.0000x reference)
//
#include <hip/hip_runtime.h>

typedef unsigned short u16;
typedef unsigned int   u32;
typedef float  f32x4  __attribute__((ext_vector_type(4)));
typedef __bf16 bf16x8 __attribute__((ext_vector_type(8)));

#define DEV static __device__ __forceinline__

DEV float bf2f(u16 u){ union{float f;u32 i;}v; v.i=((u32)u)<<16; return v.f; }
DEV float bflo(u32 u){ union{float f;u32 i;}v; v.i=u<<16; return v.f; }
DEV float bfhi(u32 u){ union{float f;u32 i;}v; v.i=u&0xffff0000u; return v.f; }
DEV u16   f2bf(float f){ union{float f;u32 i;}v; v.f=f; return (u16)((v.i + 0x7fffu + ((v.i>>16)&1u))>>16); }

DEV void async16(const void* g, void* l){
  __builtin_amdgcn_global_load_lds((const __attribute__((address_space(1))) void*)g,
                                   (__attribute__((address_space(3))) void*)l, 16, 0, 0);
}

// ---------------- cast fp32 -> bf16 (4 elems/thread) ----------------
__global__ __launch_bounds__(256) void cast_bf16(const float* __restrict__ in,
                                                 u16* __restrict__ out, int n4)
{
  int i = blockIdx.x*256 + threadIdx.x;
  if (i >= n4) return;
  float4 v = ((const float4*)in)[i];
  ushort4 o;
  o.x = f2bf(v.x); o.y = f2bf(v.y); o.z = f2bf(v.z); o.w = f2bf(v.w);
  ((ushort4*)out)[i] = o;
}

// ---------------- bf16 MFMA GEMM, C[m][n] = sum_k A[m][k]*W[n][k] ----------------
// 128x128 tile, BK=32, 4 waves (2x2), 4x4 MFMA subtiles per wave. M,N multiples of 128.
// mode 0: split-store q/k/v bf16 (N=1536). mode 1: fp32 out + bias (N=512).
__global__ __launch_bounds__(256) void gemm_bt(
    const u16* __restrict__ A, const u16* __restrict__ W, int K, int mode,
    u16* __restrict__ oq, u16* __restrict__ okk, u16* __restrict__ ov,
    float* __restrict__ of, const float* __restrict__ bias)
{
  __shared__ __align__(16) u16 As[4096];
  __shared__ __align__(16) u16 Bs[4096];
  const int tid  = threadIdx.x;
  const int wave = tid >> 6, lane = tid & 63;
  const int wm = wave >> 1, wn = wave & 1;
  const int r16 = lane & 15, q4 = lane >> 4;
  const size_t Abase = (size_t)blockIdx.x * 128 * K;
  const size_t Bbase = (size_t)blockIdx.y * 128 * K;

  f32x4 acc[4][4];
  #pragma unroll
  for (int i=0;i<4;i++)
    #pragma unroll
    for (int j=0;j<4;j++) acc[i][j] = (f32x4){0.f,0.f,0.f,0.f};

  for (int k0 = 0; k0 < K; k0 += 32) {
    #pragma unroll
    for (int i=0;i<2;i++){
      int c   = wave*128 + i*64 + lane;     // 16B chunk id; lds dst = uniform base + lane*16
      int row = c >> 2, kc = (c & 3) * 8;
      async16(A + Abase + (size_t)row*K + k0 + kc, (char*)As + (wave*128 + i*64)*16);
      async16(W + Bbase + (size_t)row*K + k0 + kc, (char*)Bs + (wave*128 + i*64)*16);
    }
    __syncthreads();
    bf16x8 af[4], bfr[4];
    #pragma unroll
    for (int i=0;i<4;i++) af[i]  = *(const bf16x8*)&As[(wm*64 + i*16 + r16)*32 + q4*8];
    #pragma unroll
    for (int j=0;j<4;j++) bfr[j] = *(const bf16x8*)&Bs[(wn*64 + j*16 + r16)*32 + q4*8];
    #pragma unroll
    for (int i=0;i<4;i++)
      #pragma unroll
      for (int j=0;j<4;j++)
        acc[i][j] = __builtin_amdgcn_mfma_f32_16x16x32_bf16(af[i], bfr[j], acc[i][j], 0,0,0);
    __syncthreads();
  }

  const int m0 = blockIdx.x*128 + wm*64;
  const int n0 = blockIdx.y*128 + wn*64;
  #pragma unroll
  for (int i=0;i<4;i++)
    #pragma unroll
    for (int j=0;j<4;j++)
      #pragma unroll
      for (int r=0;r<4;r++){
        int m = m0 + i*16 + q4*4 + r;       // C/D: col=lane&15, row=(lane>>4)*4+reg  [m89]
        int n = n0 + j*16 + r16;
        float val = acc[i][j][r];
        if (mode == 0){
          int sel = n >> 9, col = n & 511;
          u16* dst = sel==0 ? oq : (sel==1 ? okk : ov);
          dst[(size_t)m*512 + col] = f2bf(val);
        } else {
          of[(size_t)m*512 + n] = val + bias[n];
        }
      }
}

// ---------------- agent pooling: exact 8x8 block mean of q ----------------
__global__ __launch_bounds__(256) void pool_q(const u16* __restrict__ qb, u16* __restrict__ agentb)
{
  int idx = blockIdx.x*256 + threadIdx.x;          // 16*49*512
  int c = idx & 511;
  int ba = idx >> 9;
  int a = ba % 49, b = ba / 49;
  int ay = a / 7, ax = a % 7;
  const u16* base = qb + (size_t)b*3136*512 + c;
  float acc = 0.f;
  #pragma unroll
  for (int iy=0; iy<8; iy++){
    int rowoff = ((ay*8 + iy)*56 + ax*8) * 512;
    #pragma unroll
    for (int ix=0; ix<8; ix++) acc += bf2f(base[(size_t)rowoff + ix*512]);
  }
  agentb[idx] = f2bf(acc * 0.015625f);
}

// ---------------- bias tables: PB[8][49][196], AB[8][197][49] ----------------
DEV void lin1(float c, int S, int& i0, int& i1, float& w){
  if (c <= 0.f){ i0=0; i1=0; w=0.f; }
  else if (c >= (float)(S-1)){ i0=S-1; i1=S-1; w=0.f; }
  else { i0=(int)c; i1=i0+1; w=c-(float)i0; }
}
DEV float bilin7(const float* s, int Y, int X){
  int y0,y1,x0,x1; float wy,wx;
  lin1(0.5f*Y - 0.25f, 7, y0,y1,wy);
  lin1(0.5f*X - 0.25f, 7, x0,x1,wx);
  float v0 = s[y0*7+x0] + wx*(s[y0*7+x1]-s[y0*7+x0]);
  float v1 = s[y1*7+x0] + wx*(s[y1*7+x1]-s[y1*7+x0]);
  return v0 + wy*(v1 - v0);
}
__global__ __launch_bounds__(256) void bias_pre(
    const float* __restrict__ an_bias, const float* __restrict__ na_bias,
    const float* __restrict__ ah_bias, const float* __restrict__ aw_bias,
    const float* __restrict__ ha_bias, const float* __restrict__ wa_bias,
    const float* __restrict__ ca_bias, float* __restrict__ PB, float* __restrict__ AB)
{
  int idx = blockIdx.x*256 + threadIdx.x;
  if (idx < 8*49*196){
    int j = idx % 196; int ha = idx / 196; int a = ha % 49, h = ha / 49;
    int wy = j / 14, wx = j % 14;
    PB[idx] = bilin7(an_bias + (h*49+a)*49, wy, wx)
            + ah_bias[(h*49+a)*14 + wy] + aw_bias[(h*49+a)*14 + wx];
  }
  int idx2 = idx - 8*49*196;
  if (idx2 >= 0 && idx2 < 8*197*49){
    int a = idx2 % 49; int hr = idx2 / 49; int r = hr % 197, h = hr / 197;
    float v;
    if (r == 0) v = ca_bias[h*49 + a];
    else {
      int j = r - 1; int wy = j / 14, wx = j % 14;
      v = bilin7(na_bias + (h*49+a)*49, wy, wx)
        + ha_bias[(h*14+wy)*49 + a] + wa_bias[(h*14+wx)*49 + a];
    }
    AB[idx2] = v;
  }
}

// ---------------- stage 1: scores + softmax over n (max-free; scores tiny) ----------------
__global__ __launch_bounds__(256) void stage1_attn(
    const u16* __restrict__ kb, const u16* __restrict__ agentb,
    const float* __restrict__ PB, u16* __restrict__ attn1)
{
  int blk = blockIdx.x;                 // = bh*49 + a
  int a = blk % 49, bh = blk / 49;
  int h = bh & 7, b = bh >> 3;
  __shared__ float ah[64];
  __shared__ float pbrow[196];
  __shared__ float red[4];
  int tid = threadIdx.x;
  if (tid < 64) ah[tid] = bf2f(agentb[((size_t)(b*49 + a) << 9) + (h << 6) + tid]);
  for (int e = tid; e < 196; e += 256) pbrow[e] = PB[(h*49 + a)*196 + e];
  __syncthreads();
  const u16* kbase = kb + (size_t)b*3136*512 + h*64;
  float s[13];
  float lsum = 0.f;
  #pragma unroll
  for (int i = 0; i < 13; i++) {
    int n = tid + (i << 8);
    float e = 0.f;
    if (n < 3136) {
      const uint4* kr = (const uint4*)(kbase + (size_t)n*512);
      float acc = 0.f;
      #pragma unroll
      for (int ch = 0; ch < 8; ch++) {
        uint4 u = kr[ch];
        int o = ch*8;
        acc += bflo(u.x)*ah[o+0] + bfhi(u.x)*ah[o+1]
             + bflo(u.y)*ah[o+2] + bfhi(u.y)*ah[o+3]
             + bflo(u.z)*ah[o+4] + bfhi(u.z)*ah[o+5]
             + bflo(u.w)*ah[o+6] + bfhi(u.w)*ah[o+7];
      }
      // pb_up: 1-D half-pixel linear interp over flattened 196 (jax.image.resize semantics)
      float c1 = (n + 0.5f)*0.0625f - 0.5f;
      float bias;
      if (c1 <= 0.f) bias = pbrow[0];
      else if (c1 >= 195.f) bias = pbrow[195];
      else { int j0 = (int)c1; float w = c1 - (float)j0; bias = pbrow[j0] + w*(pbrow[j0+1]-pbrow[j0]); }
      e = __expf(0.125f*acc + bias);
    }
    s[i] = e; lsum += e;
  }
  #pragma unroll
  for (int m = 32; m > 0; m >>= 1) lsum += __shfl_xor(lsum, m);
  if ((tid & 63) == 0) red[tid >> 6] = lsum;
  __syncthreads();
  float inv = 1.f / (red[0] + red[1] + red[2] + red[3]);
  u16* arow = attn1 + (size_t)blk * 3136;
  #pragma unroll
  for (int i = 0; i < 13; i++) {
    int n = tid + (i << 8);
    if (n < 3136) arow[n] = f2bf(s[i] * inv);
  }
}

// ---------------- stage 1 PV: agent_v partials over 8 n-chunks ----------------
__global__ __launch_bounds__(256) void stage1_pv(
    const u16* __restrict__ attn1, const u16* __restrict__ vb, float* __restrict__ part)
{
  int bh = blockIdx.x, chunk = blockIdx.y;
  int b = bh >> 3, h = bh & 7;
  int tid = threadIdx.x;
  __shared__ __align__(16) u16 vt[16384];     // 256 x 64
  __shared__ __align__(16) u16 at[12544];     // 49 x 256
  int d = tid & 63, a0 = tid >> 6;            // a0 = wave id (uniform per wave)
  float acc[13];
  #pragma unroll
  for (int i = 0; i < 13; i++) acc[i] = 0.f;
  const u16* ab_ = attn1 + (size_t)bh*49*3136;
  for (int t = 0; t < 2; t++) {
    int n0 = chunk*392 + t*256;
    int cnt = 392 - t*256; if (cnt > 256) cnt = 256;
    __syncthreads();
    #pragma unroll
    for (int i = 0; i < 8; i++) {
      int e = tid + (i << 8);
      int r = e >> 3, dc = (e & 7) * 8;
      int n = n0 + r; if (n > 3135) n = 3135;
      *(uint4*)&vt[r*64 + dc] = *(const uint4*)(vb + ((size_t)b*3136 + n)*512 + h*64 + dc);
    }
    for (int i = 0; i < 49; i++)
      at[(i << 8) + tid] = (tid < cnt) ? ab_[(size_t)i*3136 + n0 + tid] : (u16)0;
    __syncthreads();
    for (int j = 0; j < 256; j++) {
      float vv = bf2f(vt[j*64 + d]);
      #pragma unroll
      for (int i = 0; i < 12; i++)
        acc[i] += bf2f(at[((a0 + (i << 2)) << 8) + j]) * vv;  // broadcast reads
      if (a0 == 0) acc[12] += bf2f(at[(48 << 8) + j]) * vv;
    }
  }
  float* pp = part + ((size_t)chunk*128 + bh)*3136;           // 49*64 = 3136
  #pragma unroll
  for (int i = 0; i < 12; i++) pp[(a0 + (i << 2))*64 + d] = acc[i];
  if (a0 == 0) pp[48*64 + d] = acc[12];
}

__global__ __launch_bounds__(256) void reduce_pv(const float* __restrict__ part, float* __restrict__ agv)
{
  int idx = blockIdx.x*256 + threadIdx.x;   // 128*49*64
  float acc = 0.f;
  #pragma unroll
  for (int c = 0; c < 8; c++) acc += part[(size_t)c*401408 + idx];
  agv[idx] = acc;
}

// ---------------- stage 2: fused q->agent attention + PV (max-free softmax over 49) ----------------
__global__ __launch_bounds__(256) void stage2_out(
    const u16* __restrict__ qb, const u16* __restrict__ agentb,
    const float* __restrict__ agv, const float* __restrict__ AB,
    u16* __restrict__ aout)
{
  int bh = blockIdx.y, b = bh >> 3, h = bh & 7;
  int tid = threadIdx.x;
  __shared__ float ah_s[3136];
  __shared__ float av_s[3136];
  __shared__ float ab_s[9653];
  for (int e = tid; e < 3136; e += 256) {
    int a = e >> 6, dd = e & 63;
    ah_s[e] = bf2f(agentb[((size_t)(b*49 + a) << 9) + (h << 6) + dd]);
    av_s[e] = agv[(size_t)bh*3136 + e];
  }
  for (int e = tid; e < 9653; e += 256) ab_s[e] = AB[(size_t)h*9653 + e];
  __syncthreads();
  int n = blockIdx.x*256 + tid;
  if (n >= 3136) return;
  float qr[64];
  const uint4* qp = (const uint4*)(qb + ((size_t)b*3136 + n)*512 + h*64);
  #pragma unroll
  for (int ch = 0; ch < 8; ch++) {
    uint4 u = qp[ch]; int o = ch*8;
    qr[o+0]=bflo(u.x); qr[o+1]=bfhi(u.x); qr[o+2]=bflo(u.y); qr[o+3]=bfhi(u.y);
    qr[o+4]=bflo(u.z); qr[o+5]=bfhi(u.z); qr[o+6]=bflo(u.w); qr[o+7]=bfhi(u.w);
  }
  // ab_up: rows 0..196 (row0 = ca), half-pixel interp 197 -> 3136
  float c2 = (n + 0.5f)*(197.0f/3136.0f) - 0.5f;
  int r0; float w;
  if (c2 <= 0.f) { r0 = 0; w = 0.f; }
  else if (c2 >= 196.f) { r0 = 196; w = 0.f; }
  else { r0 = (int)c2; w = c2 - (float)r0; }
  int r1 = (r0 < 196) ? r0 + 1 : 196;
  const float* ab0 = &ab_s[r0*49];
  const float* ab1 = &ab_s[r1*49];
  float sum = 0.f;
  float oa[64];
  #pragma unroll
  for (int dd = 0; dd < 64; dd++) oa[dd] = 0.f;
  for (int a = 0; a < 49; a++) {
    const float* ar = &ah_s[a << 6];
    float acc = 0.f;
    #pragma unroll
    for (int dd = 0; dd < 64; dd++) acc += qr[dd]*ar[dd];
    float e = __expf(0.125f*acc + ab0[a] + w*(ab1[a] - ab0[a]));
    sum += e;
    const float* avr = &av_s[a << 6];
    #pragma unroll
    for (int dd = 0; dd < 64; dd++) oa[dd] += e*avr[dd];
  }
  float inv = 1.f/sum;
  u16* op = aout + ((size_t)b*3136 + n)*512 + h*64;
  #pragma unroll
  for (int dc = 0; dc < 64; dc += 8) {
    uint4 pk;
    pk.x = (u32)f2bf(oa[dc+0]*inv) | ((u32)f2bf(oa[dc+1]*inv) << 16);
    pk.y = (u32)f2bf(oa[dc+2]*inv) | ((u32)f2bf(oa[dc+3]*inv) << 16);
    pk.z = (u32)f2bf(oa[dc+4]*inv) | ((u32)f2bf(oa[dc+5]*inv) << 16);
    pk.w = (u32)f2bf(oa[dc+6]*inv) | ((u32)f2bf(oa[dc+7]*inv) << 16);
    *(uint4*)(op + dc) = pk;
  }
}

// ---------------- depthwise 3x3 conv on v + residual add (in place) ----------------
__global__ __launch_bounds__(256) void dwc_add(
    const u16* __restrict__ vb, const float* __restrict__ w_dwc,
    const float* __restrict__ b_dwc, u16* __restrict__ io)
{
  size_t idx = (size_t)blockIdx.x*256 + threadIdx.x;   // 16*3136*512
  int c = (int)(idx & 511);
  size_t bn = idx >> 9;
  int n = (int)(bn % 3136);
  int b = (int)(bn / 3136);
  int y = n / 56, x = n % 56;
  float acc = bf2f(io[idx]) + b_dwc[c];
  const float* wc = w_dwc + c*9;
  const u16* vbase = vb + (size_t)b*3136*512 + c;
  #pragma unroll
  for (int dy = 0; dy < 3; dy++) {
    int yy = y + dy - 1;
    if (yy < 0 || yy > 55) continue;
    #pragma unroll
    for (int dx = 0; dx < 3; dx++) {
      int xx = x + dx - 1;
      if (xx < 0 || xx > 55) continue;
      acc += bf2f(vbase[(size_t)(yy*56 + xx) << 9]) * wc[dy*3 + dx];
    }
  }
  io[idx] = f2bf(acc);
}

extern "C" void kernel_launch(void* const* d_in, const int* in_sizes, int n_in,
                              void* d_out, int out_size, void* d_ws, size_t ws_size,
                              hipStream_t stream)
{
  const float* x       = (const float*)d_in[0];
  const float* w_qkv   = (const float*)d_in[1];
  const float* w_proj  = (const float*)d_in[2];
  const float* b_proj  = (const float*)d_in[3];
  const float* w_dwc   = (const float*)d_in[4];
  const float* b_dwc   = (const float*)d_in[5];
  const float* an_bias = (const float*)d_in[6];
  const float* na_bias = (const float*)d_in[7];
  const float* ah_bias = (const float*)d_in[8];
  const float* aw_bias = (const float*)d_in[9];
  const float* ha_bias = (const float*)d_in[10];
  const float* wa_bias = (const float*)d_in[11];
  const float* ca_bias = (const float*)d_in[12];

  if (ws_size < 223500000u) return;   // need ~213.2 MiB

  char* p = (char*)d_ws;
  u16* regA   = (u16*)p;  p += 51380224;   // xb -> attn1 -> attn_out (lifetimes disjoint)
  u16* qb     = (u16*)p;  p += 51380224;
  u16* kb     = (u16*)p;  p += 51380224;
  u16* vb     = (u16*)p;  p += 51380224;
  u16* wqkvb  = (u16*)p;  p += 1572864;
  u16* wprojb = (u16*)p;  p += 524288;
  u16* agentb = (u16*)p;  p += 802816;
  float* PB   = (float*)p; p += 307456;
  float* AB   = (float*)p; p += 309248;
  float* part = (float*)p; p += 12845056;
  float* agv  = (float*)p; p += 1605632;

  cast_bf16<<<25088, 256, 0, stream>>>(x, regA, 6422528);
  cast_bf16<<<768,   256, 0, stream>>>(w_qkv, wqkvb, 196608);
  cast_bf16<<<256,   256, 0, stream>>>(w_proj, wprojb, 65536);

  gemm_bt<<<dim3(392,12), 256, 0, stream>>>(regA, wqkvb, 512, 0, qb, kb, vb, nullptr, nullptr);
  pool_q<<<1568, 256, 0, stream>>>(qb, agentb);
  bias_pre<<<602, 256, 0, stream>>>(an_bias, na_bias, ah_bias, aw_bias, ha_bias, wa_bias, ca_bias, PB, AB);
  stage1_attn<<<6272, 256, 0, stream>>>(kb, agentb, PB, regA);
  stage1_pv<<<dim3(128,8), 256, 0, stream>>>(regA, vb, part);
  reduce_pv<<<1568, 256, 0, stream>>>(part, agv);
  stage2_out<<<dim3(13,128), 256, 0, stream>>>(qb, agentb, agv, AB, regA);
  dwc_add<<<100352, 256, 0, stream>>>(vb, w_dwc, b_dwc, regA);
  gemm_bt<<<dim3(392,4), 256, 0, stream>>>(regA, wprojb, 512, 1, nullptr, nullptr, nullptr,
                                           (float*)d_out, b_proj);
}

// Round 2
// 933.052 us; speedup vs baseline: 2.7536x; 2.7536x over previous
//
#include <hip/hip_runtime.h>

typedef unsigned short u16;
typedef unsigned int   u32;
typedef float  f32x4  __attribute__((ext_vector_type(4)));
typedef __bf16 bf16x8 __attribute__((ext_vector_type(8)));

#define DEV static __device__ __forceinline__

DEV float bf2f(u16 u){ union{float f;u32 i;}v; v.i=((u32)u)<<16; return v.f; }
DEV float bflo(u32 u){ union{float f;u32 i;}v; v.i=u<<16; return v.f; }
DEV float bfhi(u32 u){ union{float f;u32 i;}v; v.i=u&0xffff0000u; return v.f; }
DEV u16   f2bf(float f){ union{float f;u32 i;}v; v.f=f; return (u16)((v.i + 0x7fffu + ((v.i>>16)&1u))>>16); }

DEV void async16(const void* g, void* l){
  __builtin_amdgcn_global_load_lds((const __attribute__((address_space(1))) void*)g,
                                   (__attribute__((address_space(3))) void*)l, 16, 0, 0);
}

// ---------------- cast fp32 -> bf16 (4 elems/thread) ----------------
__global__ __launch_bounds__(256) void cast_bf16(const float* __restrict__ in,
                                                 u16* __restrict__ out, int n4)
{
  int i = blockIdx.x*256 + threadIdx.x;
  if (i >= n4) return;
  float4 v = ((const float4*)in)[i];
  ushort4 o;
  o.x = f2bf(v.x); o.y = f2bf(v.y); o.z = f2bf(v.z); o.w = f2bf(v.w);
  ((ushort4*)out)[i] = o;
}

// ---------------- bf16 MFMA GEMM, C[m][n] = sum_k A[m][k]*W[n][k] ----------------
__global__ __launch_bounds__(256) void gemm_bt(
    const u16* __restrict__ A, const u16* __restrict__ W, int K, int mode,
    u16* __restrict__ oq, u16* __restrict__ okk, u16* __restrict__ ov,
    float* __restrict__ of, const float* __restrict__ bias)
{
  __shared__ __align__(16) u16 As[4096];
  __shared__ __align__(16) u16 Bs[4096];
  const int tid  = threadIdx.x;
  const int wave = tid >> 6, lane = tid & 63;
  const int wm = wave >> 1, wn = wave & 1;
  const int r16 = lane & 15, q4 = lane >> 4;
  const size_t Abase = (size_t)blockIdx.x * 128 * K;
  const size_t Bbase = (size_t)blockIdx.y * 128 * K;

  f32x4 acc[4][4];
  #pragma unroll
  for (int i=0;i<4;i++)
    #pragma unroll
    for (int j=0;j<4;j++) acc[i][j] = (f32x4){0.f,0.f,0.f,0.f};

  for (int k0 = 0; k0 < K; k0 += 32) {
    #pragma unroll
    for (int i=0;i<2;i++){
      int c   = wave*128 + i*64 + lane;
      int row = c >> 2, kc = (c & 3) * 8;
      async16(A + Abase + (size_t)row*K + k0 + kc, (char*)As + (wave*128 + i*64)*16);
      async16(W + Bbase + (size_t)row*K + k0 + kc, (char*)Bs + (wave*128 + i*64)*16);
    }
    __syncthreads();
    bf16x8 af[4], bfr[4];
    #pragma unroll
    for (int i=0;i<4;i++) af[i]  = *(const bf16x8*)&As[(wm*64 + i*16 + r16)*32 + q4*8];
    #pragma unroll
    for (int j=0;j<4;j++) bfr[j] = *(const bf16x8*)&Bs[(wn*64 + j*16 + r16)*32 + q4*8];
    #pragma unroll
    for (int i=0;i<4;i++)
      #pragma unroll
      for (int j=0;j<4;j++)
        acc[i][j] = __builtin_amdgcn_mfma_f32_16x16x32_bf16(af[i], bfr[j], acc[i][j], 0,0,0);
    __syncthreads();
  }

  const int m0 = blockIdx.x*128 + wm*64;
  const int n0 = blockIdx.y*128 + wn*64;
  #pragma unroll
  for (int i=0;i<4;i++)
    #pragma unroll
    for (int j=0;j<4;j++)
      #pragma unroll
      for (int r=0;r<4;r++){
        int m = m0 + i*16 + q4*4 + r;
        int n = n0 + j*16 + r16;
        float val = acc[i][j][r];
        if (mode == 0){
          int sel = n >> 9, col = n & 511;
          u16* dst = sel==0 ? oq : (sel==1 ? okk : ov);
          dst[(size_t)m*512 + col] = f2bf(val);
        } else {
          of[(size_t)m*512 + n] = val + bias[n];
        }
      }
}

// ---------------- agent pooling: exact 8x8 block mean of q ----------------
__global__ __launch_bounds__(256) void pool_q(const u16* __restrict__ qb, u16* __restrict__ agentb)
{
  int idx = blockIdx.x*256 + threadIdx.x;          // 16*49*512
  int c = idx & 511;
  int ba = idx >> 9;
  int a = ba % 49, b = ba / 49;
  int ay = a / 7, ax = a % 7;
  const u16* base = qb + (size_t)b*3136*512 + c;
  float acc = 0.f;
  #pragma unroll
  for (int iy=0; iy<8; iy++){
    int rowoff = ((ay*8 + iy)*56 + ax*8) * 512;
    #pragma unroll
    for (int ix=0; ix<8; ix++) acc += bf2f(base[(size_t)rowoff + ix*512]);
  }
  agentb[idx] = f2bf(acc * 0.015625f);
}

// ---------------- bias tables: PB[8][49][196], AB[8][197][49] ----------------
DEV void lin1(float c, int S, int& i0, int& i1, float& w){
  if (c <= 0.f){ i0=0; i1=0; w=0.f; }
  else if (c >= (float)(S-1)){ i0=S-1; i1=S-1; w=0.f; }
  else { i0=(int)c; i1=i0+1; w=c-(float)i0; }
}
DEV float bilin7(const float* s, int Y, int X){
  int y0,y1,x0,x1; float wy,wx;
  lin1(0.5f*Y - 0.25f, 7, y0,y1,wy);
  lin1(0.5f*X - 0.25f, 7, x0,x1,wx);
  float v0 = s[y0*7+x0] + wx*(s[y0*7+x1]-s[y0*7+x0]);
  float v1 = s[y1*7+x0] + wx*(s[y1*7+x1]-s[y1*7+x0]);
  return v0 + wy*(v1 - v0);
}
__global__ __launch_bounds__(256) void bias_pre(
    const float* __restrict__ an_bias, const float* __restrict__ na_bias,
    const float* __restrict__ ah_bias, const float* __restrict__ aw_bias,
    const float* __restrict__ ha_bias, const float* __restrict__ wa_bias,
    const float* __restrict__ ca_bias, float* __restrict__ PB, float* __restrict__ AB)
{
  int idx = blockIdx.x*256 + threadIdx.x;
  if (idx < 8*49*196){
    int j = idx % 196; int ha = idx / 196; int a = ha % 49, h = ha / 49;
    int wy = j / 14, wx = j % 14;
    PB[idx] = bilin7(an_bias + (h*49+a)*49, wy, wx)
            + ah_bias[(h*49+a)*14 + wy] + aw_bias[(h*49+a)*14 + wx];
  }
  int idx2 = idx - 8*49*196;
  if (idx2 >= 0 && idx2 < 8*197*49){
    int a = idx2 % 49; int hr = idx2 / 49; int r = hr % 197, h = hr / 197;
    float v;
    if (r == 0) v = ca_bias[h*49 + a];
    else {
      int j = r - 1; int wy = j / 14, wx = j % 14;
      v = bilin7(na_bias + (h*49+a)*49, wy, wx)
        + ha_bias[(h*14+wy)*49 + a] + wa_bias[(h*14+wx)*49 + a];
    }
    AB[idx2] = v;
  }
}

// ---------------- expand stage-1 bias: PBI[h][a][n], 1-D half-pixel interp 196->3136 ----------------
__global__ __launch_bounds__(256) void bias_expand(const float* __restrict__ PB, float* __restrict__ PBI)
{
  int idx = blockIdx.x*256 + threadIdx.x;   // 8*49*3136
  if (idx >= 1229312) return;
  int n = idx % 3136; int ha = idx / 3136;
  const float* row = PB + ha*196;
  float c1 = (n + 0.5f)*0.0625f - 0.5f;
  float bias;
  if (c1 <= 0.f) bias = row[0];
  else if (c1 >= 195.f) bias = row[195];
  else { int j0 = (int)c1; float w = c1 - (float)j0; bias = row[j0] + w*(row[j0+1]-row[j0]); }
  PBI[idx] = bias;
}

// ---------------- fused stage 1: scores+exp (LDS) then PV, per (bh, 196-n chunk) ----------------
// outputs unnormalized partials pav[chunk][bh][49][64] and exp-sums psum[chunk][bh][49]
__global__ __launch_bounds__(256) void stage1_fused(
    const u16* __restrict__ kb, const u16* __restrict__ vb,
    const u16* __restrict__ agentb, const float* __restrict__ PBI,
    float* __restrict__ pav, float* __restrict__ psum)
{
  int bh = blockIdx.x, chunk = blockIdx.y;
  int b = bh >> 3, h = bh & 7;
  int n0 = chunk * 196;
  __shared__ __align__(16) u16 kv[196*72];     // 28224 B, k then v (stride 72 keeps 16B align)
  __shared__ float ah_s[3136];                 // 12544 B
  __shared__ u16 scb[49*196];                  // 19208 B, exp-scores bf16
  int tid = threadIdx.x;
  int lane = tid & 63, wave = tid >> 6;

  for (int e = tid; e < 1568; e += 256) {      // 196 rows x 8 chunks of 16B
    int r = e >> 3, c = (e & 7) * 8;
    *(uint4*)&kv[r*72 + c] = *(const uint4*)(kb + ((size_t)(b*3136 + n0 + r))*512 + h*64 + c);
  }
  for (int e = tid; e < 3136; e += 256)
    ah_s[e] = bf2f(agentb[(((size_t)(b*49 + (e >> 6))) << 9) + (h << 6) + (e & 63)]);
  __syncthreads();

  // phase A: one token per thread (196 active)
  if (tid < 196) {
    float kr[64];
    #pragma unroll
    for (int cc = 0; cc < 8; cc++) {
      uint4 u = *(const uint4*)&kv[tid*72 + cc*8];
      int o = cc*8;
      kr[o+0]=bflo(u.x); kr[o+1]=bfhi(u.x); kr[o+2]=bflo(u.y); kr[o+3]=bfhi(u.y);
      kr[o+4]=bflo(u.z); kr[o+5]=bfhi(u.z); kr[o+6]=bflo(u.w); kr[o+7]=bfhi(u.w);
    }
    const float* pbase = PBI + (size_t)h*49*3136 + n0 + tid;
    for (int a = 0; a < 49; a++) {
      const float* ar = &ah_s[a << 6];
      float acc = 0.f;
      #pragma unroll
      for (int dd = 0; dd < 64; dd++) acc += kr[dd]*ar[dd];
      float e = __expf(0.125f*acc + pbase[(size_t)a*3136]);
      scb[a*196 + tid] = f2bf(e);
    }
  }
  __syncthreads();
  for (int e = tid; e < 1568; e += 256) {      // reload v over k
    int r = e >> 3, c = (e & 7) * 8;
    *(uint4*)&kv[r*72 + c] = *(const uint4*)(vb + ((size_t)(b*3136 + n0 + r))*512 + h*64 + c);
  }
  __syncthreads();

  // phase B: wave w owns agents {w, w+4, ...}; lane = dim
  int d = lane;
  float acc[13], ssum[13];
  #pragma unroll
  for (int i = 0; i < 13; i++) { acc[i] = 0.f; ssum[i] = 0.f; }
  for (int j = 0; j < 196; j += 4) {
    float vv0 = bf2f(kv[(j+0)*72 + d]);
    float vv1 = bf2f(kv[(j+1)*72 + d]);
    float vv2 = bf2f(kv[(j+2)*72 + d]);
    float vv3 = bf2f(kv[(j+3)*72 + d]);
    #pragma unroll
    for (int i = 0; i < 12; i++) {
      int a = wave + (i << 2);
      uint2 p4 = *(const uint2*)&scb[a*196 + j];
      float p0=bflo(p4.x), p1=bfhi(p4.x), p2=bflo(p4.y), p3=bfhi(p4.y);
      acc[i]  += p0*vv0 + p1*vv1 + p2*vv2 + p3*vv3;
      ssum[i] += (p0+p1) + (p2+p3);
    }
    if (wave == 0) {
      uint2 p4 = *(const uint2*)&scb[48*196 + j];
      float p0=bflo(p4.x), p1=bfhi(p4.x), p2=bflo(p4.y), p3=bfhi(p4.y);
      acc[12]  += p0*vv0 + p1*vv1 + p2*vv2 + p3*vv3;
      ssum[12] += (p0+p1) + (p2+p3);
    }
  }
  size_t pbase = ((size_t)chunk*128 + bh)*3136;
  size_t sbase = ((size_t)chunk*128 + bh)*49;
  #pragma unroll
  for (int i = 0; i < 12; i++) {
    int a = wave + (i << 2);
    pav[pbase + a*64 + d] = acc[i];
    if (d == 0) psum[sbase + a] = ssum[i];
  }
  if (wave == 0) {
    pav[pbase + 48*64 + d] = acc[12];
    if (d == 0) psum[sbase + 48] = ssum[12];
  }
}

// ---------------- normalize+reduce partials -> agent_v fp32 ----------------
__global__ __launch_bounds__(256) void reduce_agv(
    const float* __restrict__ pav, const float* __restrict__ psum, float* __restrict__ agv)
{
  int idx = blockIdx.x*256 + threadIdx.x;   // 128*3136
  int bh = idx / 3136, r = idx % 3136, a = r >> 6;
  float acc = 0.f, s = 0.f;
  #pragma unroll
  for (int c = 0; c < 16; c++) {
    acc += pav[((size_t)c*128 + bh)*3136 + r];
    s   += psum[((size_t)c*128 + bh)*49 + a];
  }
  agv[idx] = acc / s;
}

// ---------------- stage 2: fused q->agent attention + PV ----------------
__global__ __launch_bounds__(256) void stage2_out(
    const u16* __restrict__ qb, const u16* __restrict__ agentb,
    const float* __restrict__ agv, const float* __restrict__ AB,
    u16* __restrict__ aout)
{
  int bh = blockIdx.y, b = bh >> 3, h = bh & 7;
  int tid = threadIdx.x;
  __shared__ float ah_s[3136];
  __shared__ float av_s[3136];
  __shared__ float ab_s[9653];
  for (int e = tid; e < 3136; e += 256) {
    int a = e >> 6, dd = e & 63;
    ah_s[e] = bf2f(agentb[(((size_t)(b*49 + a)) << 9) + (h << 6) + dd]);
    av_s[e] = agv[(size_t)bh*3136 + e];
  }
  for (int e = tid; e < 9653; e += 256) ab_s[e] = AB[(size_t)h*9653 + e];
  __syncthreads();
  int n = blockIdx.x*256 + tid;
  if (n >= 3136) return;
  float qr[64];
  const uint4* qp = (const uint4*)(qb + ((size_t)b*3136 + n)*512 + h*64);
  #pragma unroll
  for (int ch = 0; ch < 8; ch++) {
    uint4 u = qp[ch]; int o = ch*8;
    qr[o+0]=bflo(u.x); qr[o+1]=bfhi(u.x); qr[o+2]=bflo(u.y); qr[o+3]=bfhi(u.y);
    qr[o+4]=bflo(u.z); qr[o+5]=bfhi(u.z); qr[o+6]=bflo(u.w); qr[o+7]=bfhi(u.w);
  }
  float c2 = (n + 0.5f)*(197.0f/3136.0f) - 0.5f;
  int r0; float w;
  if (c2 <= 0.f) { r0 = 0; w = 0.f; }
  else if (c2 >= 196.f) { r0 = 196; w = 0.f; }
  else { r0 = (int)c2; w = c2 - (float)r0; }
  int r1 = (r0 < 196) ? r0 + 1 : 196;
  const float* ab0 = &ab_s[r0*49];
  const float* ab1 = &ab_s[r1*49];
  float sum = 0.f;
  float oa[64];
  #pragma unroll
  for (int dd = 0; dd < 64; dd++) oa[dd] = 0.f;
  for (int a = 0; a < 49; a++) {
    const float* ar = &ah_s[a << 6];
    float acc = 0.f;
    #pragma unroll
    for (int dd = 0; dd < 64; dd++) acc += qr[dd]*ar[dd];
    float e = __expf(0.125f*acc + ab0[a] + w*(ab1[a] - ab0[a]));
    sum += e;
    const float* avr = &av_s[a << 6];
    #pragma unroll
    for (int dd = 0; dd < 64; dd++) oa[dd] += e*avr[dd];
  }
  float inv = 1.f/sum;
  u16* op = aout + ((size_t)b*3136 + n)*512 + h*64;
  #pragma unroll
  for (int dc = 0; dc < 64; dc += 8) {
    uint4 pk;
    pk.x = (u32)f2bf(oa[dc+0]*inv) | ((u32)f2bf(oa[dc+1]*inv) << 16);
    pk.y = (u32)f2bf(oa[dc+2]*inv) | ((u32)f2bf(oa[dc+3]*inv) << 16);
    pk.z = (u32)f2bf(oa[dc+4]*inv) | ((u32)f2bf(oa[dc+5]*inv) << 16);
    pk.w = (u32)f2bf(oa[dc+6]*inv) | ((u32)f2bf(oa[dc+7]*inv) << 16);
    *(uint4*)(op + dc) = pk;
  }
}

// ---------------- depthwise 3x3 conv on v + residual add (in place) ----------------
__global__ __launch_bounds__(256) void dwc_add(
    const u16* __restrict__ vb, const float* __restrict__ w_dwc,
    const float* __restrict__ b_dwc, u16* __restrict__ io)
{
  size_t idx = (size_t)blockIdx.x*256 + threadIdx.x;   // 16*3136*512
  int c = (int)(idx & 511);
  size_t bn = idx >> 9;
  int n = (int)(bn % 3136);
  int b = (int)(bn / 3136);
  int y = n / 56, x = n % 56;
  float acc = bf2f(io[idx]) + b_dwc[c];
  const float* wc = w_dwc + c*9;
  const u16* vbase = vb + (size_t)b*3136*512 + c;
  #pragma unroll
  for (int dy = 0; dy < 3; dy++) {
    int yy = y + dy - 1;
    if (yy < 0 || yy > 55) continue;
    #pragma unroll
    for (int dx = 0; dx < 3; dx++) {
      int xx = x + dx - 1;
      if (xx < 0 || xx > 55) continue;
      acc += bf2f(vbase[(size_t)(yy*56 + xx) << 9]) * wc[dy*3 + dx];
    }
  }
  io[idx] = f2bf(acc);
}

extern "C" void kernel_launch(void* const* d_in, const int* in_sizes, int n_in,
                              void* d_out, int out_size, void* d_ws, size_t ws_size,
                              hipStream_t stream)
{
  const float* x       = (const float*)d_in[0];
  const float* w_qkv   = (const float*)d_in[1];
  const float* w_proj  = (const float*)d_in[2];
  const float* b_proj  = (const float*)d_in[3];
  const float* w_dwc   = (const float*)d_in[4];
  const float* b_dwc   = (const float*)d_in[5];
  const float* an_bias = (const float*)d_in[6];
  const float* na_bias = (const float*)d_in[7];
  const float* ah_bias = (const float*)d_in[8];
  const float* aw_bias = (const float*)d_in[9];
  const float* ha_bias = (const float*)d_in[10];
  const float* wa_bias = (const float*)d_in[11];
  const float* ca_bias = (const float*)d_in[12];

  if (ws_size < 223500000u) return;

  char* p = (char*)d_ws;
  u16* regA   = (u16*)p;  p += 51380224;   // xb -> {PBI,pav,psum} -> attn_out (disjoint lifetimes)
  u16* qb     = (u16*)p;  p += 51380224;
  u16* kb     = (u16*)p;  p += 51380224;
  u16* vb     = (u16*)p;  p += 51380224;
  u16* wqkvb  = (u16*)p;  p += 1572864;
  u16* wprojb = (u16*)p;  p += 524288;
  u16* agentb = (u16*)p;  p += 802816;
  float* PB   = (float*)p; p += 307456;
  float* AB   = (float*)p; p += 309248;
  p += 12845056;                            // (old part buffer, unused)
  float* agv  = (float*)p; p += 1605632;

  // regA region overlays (used between qkv-gemm and stage2_out):
  float* PBI  = (float*)((char*)regA);                 // 4,917,248 B
  float* pav  = (float*)((char*)regA + 4917248);       // 25,690,112 B
  float* psum = (float*)((char*)regA + 30607360);      // 401,408 B

  cast_bf16<<<25088, 256, 0, stream>>>(x, regA, 6422528);
  cast_bf16<<<768,   256, 0, stream>>>(w_qkv, wqkvb, 196608);
  cast_bf16<<<256,   256, 0, stream>>>(w_proj, wprojb, 65536);

  gemm_bt<<<dim3(392,12), 256, 0, stream>>>(regA, wqkvb, 512, 0, qb, kb, vb, nullptr, nullptr);
  pool_q<<<1568, 256, 0, stream>>>(qb, agentb);
  bias_pre<<<602, 256, 0, stream>>>(an_bias, na_bias, ah_bias, aw_bias, ha_bias, wa_bias, ca_bias, PB, AB);
  bias_expand<<<4802, 256, 0, stream>>>(PB, PBI);
  stage1_fused<<<dim3(128,16), 256, 0, stream>>>(kb, vb, agentb, PBI, pav, psum);
  reduce_agv<<<1568, 256, 0, stream>>>(pav, psum, agv);
  stage2_out<<<dim3(13,128), 256, 0, stream>>>(qb, agentb, agv, AB, regA);
  dwc_add<<<100352, 256, 0, stream>>>(vb, w_dwc, b_dwc, regA);
  gemm_bt<<<dim3(392,4), 256, 0, stream>>>(regA, wprojb, 512, 1, nullptr, nullptr, nullptr,
                                           (float*)d_out, b_proj);
}

// Round 3
// 680.241 us; speedup vs baseline: 3.7770x; 1.3716x over previous
//
#include <hip/hip_runtime.h>

typedef unsigned short u16;
typedef unsigned int   u32;
typedef unsigned long long u64;
typedef float  f32x4  __attribute__((ext_vector_type(4)));
typedef __bf16 bf16x8 __attribute__((ext_vector_type(8)));

#define DEV static __device__ __forceinline__

DEV float bf2f(u16 u){ union{float f;u32 i;}v; v.i=((u32)u)<<16; return v.f; }
DEV u16   f2bf(float f){ union{float f;u32 i;}v; v.f=f; return (u16)((v.i + 0x7fffu + ((v.i>>16)&1u))>>16); }

DEV void async16(const void* g, void* l){
  __builtin_amdgcn_global_load_lds((const __attribute__((address_space(1))) void*)g,
                                   (__attribute__((address_space(3))) void*)l, 16, 0, 0);
}

// ---------------- cast fp32 -> bf16 (4 elems/thread) ----------------
__global__ __launch_bounds__(256) void cast_bf16(const float* __restrict__ in,
                                                 u16* __restrict__ out, int n4)
{
  int i = blockIdx.x*256 + threadIdx.x;
  if (i >= n4) return;
  float4 v = ((const float4*)in)[i];
  ushort4 o;
  o.x = f2bf(v.x); o.y = f2bf(v.y); o.z = f2bf(v.z); o.w = f2bf(v.w);
  ((ushort4*)out)[i] = o;
}

// ---------------- bf16 MFMA GEMM, C[m][n] = sum_k A[m][k]*W[n][k] ----------------
__global__ __launch_bounds__(256) void gemm_bt(
    const u16* __restrict__ A, const u16* __restrict__ W, int K, int mode,
    u16* __restrict__ oq, u16* __restrict__ okk, u16* __restrict__ ov,
    float* __restrict__ of, const float* __restrict__ bias)
{
  __shared__ __align__(16) u16 As[4096];
  __shared__ __align__(16) u16 Bs[4096];
  const int tid  = threadIdx.x;
  const int wave = tid >> 6, lane = tid & 63;
  const int wm = wave >> 1, wn = wave & 1;
  const int r16 = lane & 15, q4 = lane >> 4;
  const size_t Abase = (size_t)blockIdx.x * 128 * K;
  const size_t Bbase = (size_t)blockIdx.y * 128 * K;

  f32x4 acc[4][4];
  #pragma unroll
  for (int i=0;i<4;i++)
    #pragma unroll
    for (int j=0;j<4;j++) acc[i][j] = (f32x4){0.f,0.f,0.f,0.f};

  for (int k0 = 0; k0 < K; k0 += 32) {
    #pragma unroll
    for (int i=0;i<2;i++){
      int c   = wave*128 + i*64 + lane;
      int row = c >> 2, kc = (c & 3) * 8;
      async16(A + Abase + (size_t)row*K + k0 + kc, (char*)As + (wave*128 + i*64)*16);
      async16(W + Bbase + (size_t)row*K + k0 + kc, (char*)Bs + (wave*128 + i*64)*16);
    }
    __syncthreads();
    bf16x8 af[4], bfr[4];
    #pragma unroll
    for (int i=0;i<4;i++) af[i]  = *(const bf16x8*)&As[(wm*64 + i*16 + r16)*32 + q4*8];
    #pragma unroll
    for (int j=0;j<4;j++) bfr[j] = *(const bf16x8*)&Bs[(wn*64 + j*16 + r16)*32 + q4*8];
    #pragma unroll
    for (int i=0;i<4;i++)
      #pragma unroll
      for (int j=0;j<4;j++)
        acc[i][j] = __builtin_amdgcn_mfma_f32_16x16x32_bf16(af[i], bfr[j], acc[i][j], 0,0,0);
    __syncthreads();
  }

  const int m0 = blockIdx.x*128 + wm*64;
  const int n0 = blockIdx.y*128 + wn*64;
  #pragma unroll
  for (int i=0;i<4;i++)
    #pragma unroll
    for (int j=0;j<4;j++)
      #pragma unroll
      for (int r=0;r<4;r++){
        int m = m0 + i*16 + q4*4 + r;
        int n = n0 + j*16 + r16;
        float val = acc[i][j][r];
        if (mode == 0){
          int sel = n >> 9, col = n & 511;
          u16* dst = sel==0 ? oq : (sel==1 ? okk : ov);
          dst[(size_t)m*512 + col] = f2bf(val);
        } else {
          of[(size_t)m*512 + n] = val + bias[n];
        }
      }
}

// ---------------- agent pooling: exact 8x8 block mean of q (64 padded slots) ----------------
__global__ __launch_bounds__(256) void pool_q(const u16* __restrict__ qb, u16* __restrict__ agentb)
{
  int idx = blockIdx.x*256 + threadIdx.x;          // 16*64*512
  int c = idx & 511;
  int ba = idx >> 9;
  int a = ba & 63, b = ba >> 6;
  if (a >= 49) { agentb[idx] = 0; return; }
  int ay = a / 7, ax = a % 7;
  const u16* base = qb + (size_t)b*3136*512 + c;
  float acc = 0.f;
  #pragma unroll
  for (int iy=0; iy<8; iy++){
    int rowoff = ((ay*8 + iy)*56 + ax*8) * 512;
    #pragma unroll
    for (int ix=0; ix<8; ix++) acc += bf2f(base[(size_t)rowoff + ix*512]);
  }
  agentb[idx] = f2bf(acc * 0.015625f);
}

// ---------------- bias tables: PB[8][49][196], AB[8][197][49] ----------------
DEV void lin1(float c, int S, int& i0, int& i1, float& w){
  if (c <= 0.f){ i0=0; i1=0; w=0.f; }
  else if (c >= (float)(S-1)){ i0=S-1; i1=S-1; w=0.f; }
  else { i0=(int)c; i1=i0+1; w=c-(float)i0; }
}
DEV float bilin7(const float* s, int Y, int X){
  int y0,y1,x0,x1; float wy,wx;
  lin1(0.5f*Y - 0.25f, 7, y0,y1,wy);
  lin1(0.5f*X - 0.25f, 7, x0,x1,wx);
  float v0 = s[y0*7+x0] + wx*(s[y0*7+x1]-s[y0*7+x0]);
  float v1 = s[y1*7+x0] + wx*(s[y1*7+x1]-s[y1*7+x0]);
  return v0 + wy*(v1 - v0);
}
__global__ __launch_bounds__(256) void bias_pre(
    const float* __restrict__ an_bias, const float* __restrict__ na_bias,
    const float* __restrict__ ah_bias, const float* __restrict__ aw_bias,
    const float* __restrict__ ha_bias, const float* __restrict__ wa_bias,
    const float* __restrict__ ca_bias, float* __restrict__ PB, float* __restrict__ AB)
{
  int idx = blockIdx.x*256 + threadIdx.x;
  if (idx < 8*49*196){
    int j = idx % 196; int ha = idx / 196; int a = ha % 49, h = ha / 49;
    int wy = j / 14, wx = j % 14;
    PB[idx] = bilin7(an_bias + (h*49+a)*49, wy, wx)
            + ah_bias[(h*49+a)*14 + wy] + aw_bias[(h*49+a)*14 + wx];
  }
  int idx2 = idx - 8*49*196;
  if (idx2 >= 0 && idx2 < 8*197*49){
    int a = idx2 % 49; int hr = idx2 / 49; int r = hr % 197, h = hr / 197;
    float v;
    if (r == 0) v = ca_bias[h*49 + a];
    else {
      int j = r - 1; int wy = j / 14, wx = j % 14;
      v = bilin7(na_bias + (h*49+a)*49, wy, wx)
        + ha_bias[(h*14+wy)*49 + a] + wa_bias[(h*14+wx)*49 + a];
    }
    AB[idx2] = v;
  }
}

// ---------------- PBIT[h][n][64]: stage-1 bias, interp 196->3136; pad agents = -1e30 ----------------
__global__ __launch_bounds__(256) void pbit_expand(const float* __restrict__ PB, float* __restrict__ PBIT)
{
  int idx = blockIdx.x*256 + threadIdx.x;   // 8*3136*64
  if (idx >= 1605632) return;
  int a = idx & 63; int t = idx >> 6; int n = t % 3136; int h = t / 3136;
  float val = -1e30f;
  if (a < 49) {
    const float* row = PB + (h*49 + a)*196;
    float c1 = (n + 0.5f)*0.0625f - 0.5f;
    if (c1 <= 0.f) val = row[0];
    else if (c1 >= 195.f) val = row[195];
    else { int j0 = (int)c1; float w = c1 - (float)j0; val = row[j0] + w*(row[j0+1]-row[j0]); }
  }
  PBIT[idx] = val;
}

// ---------------- ABI[h][n][64]: stage-2 bias, interp 197->3136; pad agents = -1e30 ----------------
__global__ __launch_bounds__(256) void abi_expand(const float* __restrict__ AB, float* __restrict__ ABI)
{
  int idx = blockIdx.x*256 + threadIdx.x;   // 8*3136*64
  if (idx >= 1605632) return;
  int a = idx & 63; int t = idx >> 6; int n = t % 3136; int h = t / 3136;
  float val = -1e30f;
  if (a < 49) {
    float c2 = (n + 0.5f)*(197.0f/3136.0f) - 0.5f;
    int r0; float w;
    if (c2 <= 0.f) { r0 = 0; w = 0.f; }
    else if (c2 >= 196.f) { r0 = 196; w = 0.f; }
    else { r0 = (int)c2; w = c2 - (float)r0; }
    int r1 = (r0 < 196) ? r0 + 1 : 196;
    float v0 = AB[(h*197 + r0)*49 + a];
    float v1 = AB[(h*197 + r1)*49 + a];
    val = v0 + w*(v1 - v0);
  }
  ABI[idx] = val;
}

// ---------------- stage 1 (MFMA): S^T = K·ah^T, exp->P (LDS), O += P·V per wave-owned agents ----
// grid (bh=128, chunk=7); block 256; outputs pav[chunk][bh][64][64], psum[chunk][bh][64]
__global__ __launch_bounds__(256) void stage1_mfma(
    const u16* __restrict__ kb, const u16* __restrict__ vb,
    const u16* __restrict__ agentb, const float* __restrict__ PBIT,
    float* __restrict__ pav, float* __restrict__ psum)
{
  int bh = blockIdx.x, chunk = blockIdx.y;
  int b = bh >> 3, h = bh & 7;
  int tid = threadIdx.x, lane = tid & 63, w = tid >> 6;
  int r16 = lane & 15, q4 = lane >> 4;
  __shared__ __align__(16) u16 kld[64*64];   // XOR-swizzled chunks
  __shared__ __align__(16) u16 vt[64*68];    // v transposed [dim][token], stride 68
  __shared__ __align__(16) u16 scb[64*72];   // P [agent][token], stride 72

  int agent = w*16 + r16;
  bf16x8 bah[2];
  {
    const u16* ap = agentb + ((size_t)(b*64 + agent))*512 + h*64 + q4*8;
    bah[0] = *(const bf16x8*)ap;
    bah[1] = *(const bf16x8*)(ap + 32);
  }
  f32x4 Oacc[4];
  #pragma unroll
  for (int nt = 0; nt < 4; nt++) Oacc[nt] = (f32x4){0.f,0.f,0.f,0.f};
  float ssum = 0.f;
  int n0 = chunk * 448;
  const u16* kbase = kb + ((size_t)b*3136)*512 + h*64;
  const u16* vbase = vb + ((size_t)b*3136)*512 + h*64;

  for (int it = 0; it < 7; it++) {
    int nt0 = n0 + it*64;
    __syncthreads();
    // stage k via async16 with XOR chunk swizzle
    #pragma unroll
    for (int i = 0; i < 2; i++) {
      int L = w*128 + i*64 + lane;
      int row = L >> 3, colc = (L & 7) ^ (row & 7);
      async16(kbase + (size_t)(nt0 + row)*512 + colc*8, (char*)kld + (w*128 + i*64)*16);
    }
    // stage v transposed
    uint4 va[2]; int vtok[2], vdc[2];
    #pragma unroll
    for (int i = 0; i < 2; i++) {
      int c = tid + i*256;
      vtok[i] = c >> 3; vdc[i] = (c & 7)*8;
      va[i] = *(const uint4*)(vbase + (size_t)(nt0 + vtok[i])*512 + vdc[i]);
    }
    #pragma unroll
    for (int i = 0; i < 2; i++) {
      u32 uu[4] = {va[i].x, va[i].y, va[i].z, va[i].w};
      #pragma unroll
      for (int e = 0; e < 4; e++) {
        vt[(vdc[i] + 2*e + 0)*68 + vtok[i]] = (u16)(uu[e] & 0xffffu);
        vt[(vdc[i] + 2*e + 1)*68 + vtok[i]] = (u16)(uu[e] >> 16);
      }
    }
    __syncthreads();
    // QK: S^T tiles (4 mtiles of tokens x wave's agent tile)
    f32x4 S[4];
    #pragma unroll
    for (int mt = 0; mt < 4; mt++) S[mt] = (f32x4){0.f,0.f,0.f,0.f};
    #pragma unroll
    for (int ks = 0; ks < 2; ks++)
      #pragma unroll
      for (int mt = 0; mt < 4; mt++) {
        int row = mt*16 + r16;
        int colc = (ks*4 + q4) ^ (row & 7);
        bf16x8 afr = *(const bf16x8*)&kld[row*64 + colc*8];
        S[mt] = __builtin_amdgcn_mfma_f32_16x16x32_bf16(afr, bah[ks], S[mt], 0,0,0);
      }
    // exp + bias, pack to scb[agent][token]
    #pragma unroll
    for (int mt = 0; mt < 4; mt++) {
      u64 pk = 0;
      #pragma unroll
      for (int r = 0; r < 4; r++) {
        int tokl = mt*16 + q4*4 + r;
        float bias = PBIT[((size_t)h*3136 + nt0 + tokl)*64 + agent];
        float e = __expf(0.125f*S[mt][r] + bias);
        ssum += e;
        pk |= ((u64)f2bf(e)) << (16*r);
      }
      *(u64*)&scb[agent*72 + mt*16 + q4*4] = pk;
    }
    // PV: O[wave agents][64 dims] += P · V
    #pragma unroll
    for (int ks = 0; ks < 2; ks++) {
      bf16x8 ap = *(const bf16x8*)&scb[agent*72 + ks*32 + q4*8];
      #pragma unroll
      for (int nt = 0; nt < 4; nt++) {
        union { bf16x8 v; uint2 u[2]; } bb;
        int dim = nt*16 + r16;
        bb.u[0] = *(const uint2*)&vt[dim*68 + ks*32 + q4*8];
        bb.u[1] = *(const uint2*)&vt[dim*68 + ks*32 + q4*8 + 4];
        Oacc[nt] = __builtin_amdgcn_mfma_f32_16x16x32_bf16(ap, bb.v, Oacc[nt], 0,0,0);
      }
    }
  }
  ssum += __shfl_xor(ssum, 16);
  ssum += __shfl_xor(ssum, 32);
  size_t pb = (size_t)chunk*128 + bh;
  #pragma unroll
  for (int nt = 0; nt < 4; nt++)
    #pragma unroll
    for (int r = 0; r < 4; r++)
      pav[(pb*64 + (w*16 + q4*4 + r))*64 + nt*16 + r16] = Oacc[nt][r];
  if (lane < 16) psum[pb*64 + w*16 + lane] = ssum;
}

// ---------------- reduce partials -> normalized agent_v, transposed bf16 avT[bh][dim][72] ----------
__global__ __launch_bounds__(256) void reduce_agv(
    const float* __restrict__ pav, const float* __restrict__ psum, u16* __restrict__ avTg)
{
  int idx = blockIdx.x*256 + threadIdx.x;   // 128*64*64
  int d = idx & 63, a = (idx >> 6) & 63, bh = idx >> 12;
  float val = 0.f;
  if (a < 49) {
    float acc = 0.f, s = 0.f;
    #pragma unroll
    for (int c = 0; c < 7; c++) {
      acc += pav[(((size_t)c*128 + bh)*64 + a)*64 + d];
      s   += psum[((size_t)c*128 + bh)*64 + a];
    }
    val = acc / s;
  }
  avTg[((size_t)bh*64 + d)*72 + a] = f2bf(val);
}

// ---------------- stage 2 (MFMA): S2 = Q·ah^T, exp->P2 (wave LDS), out = P2·AV ----------------
// grid (bh=128, chunk=7); each wave: 7 tiles of 16 tokens
__global__ __launch_bounds__(256) void stage2_mfma(
    const u16* __restrict__ qb, const u16* __restrict__ agentb,
    const u16* __restrict__ avTg, const float* __restrict__ ABI,
    u16* __restrict__ aout)
{
  int bh = blockIdx.x, chunk = blockIdx.y;
  int b = bh >> 3, h = bh & 7;
  int tid = threadIdx.x, lane = tid & 63, w = tid >> 6;
  int r16 = lane & 15, q4 = lane >> 4;
  __shared__ __align__(16) u16 avs[64*72];      // avT staged (layout identical to global)
  __shared__ __align__(16) u16 scb2[4*16*72];   // per-wave P2 [token][agent]

  const u16* avsrc = avTg + (size_t)bh*4608;
  #pragma unroll
  for (int rr = 0; rr < 3; rr++) {
    int c = rr*256 + w*64 + lane;
    if (c < 576) async16(avsrc + c*8, (char*)avs + ((size_t)rr*256 + w*64)*16);
  }
  bf16x8 bah[4][2];
  #pragma unroll
  for (int nt = 0; nt < 4; nt++) {
    const u16* ap = agentb + ((size_t)(b*64 + nt*16 + r16))*512 + h*64 + q4*8;
    bah[nt][0] = *(const bf16x8*)ap;
    bah[nt][1] = *(const bf16x8*)(ap + 32);
  }
  __syncthreads();

  u16* scw = scb2 + w*16*72;
  for (int t = 0; t < 7; t++) {
    int tok0 = (chunk*28 + w*7 + t)*16;
    bf16x8 aq[2];
    {
      const u16* qp = qb + ((size_t)b*3136 + tok0 + r16)*512 + h*64 + q4*8;
      aq[0] = *(const bf16x8*)qp;
      aq[1] = *(const bf16x8*)(qp + 32);
    }
    f32x4 S[4];
    #pragma unroll
    for (int nt = 0; nt < 4; nt++) S[nt] = (f32x4){0.f,0.f,0.f,0.f};
    #pragma unroll
    for (int ks = 0; ks < 2; ks++)
      #pragma unroll
      for (int nt = 0; nt < 4; nt++)
        S[nt] = __builtin_amdgcn_mfma_f32_16x16x32_bf16(aq[ks], bah[nt][ks], S[nt], 0,0,0);
    float rs[4] = {0.f,0.f,0.f,0.f};
    #pragma unroll
    for (int nt = 0; nt < 4; nt++)
      #pragma unroll
      for (int r = 0; r < 4; r++) {
        int tokl = q4*4 + r;
        float bias = ABI[((size_t)h*3136 + tok0 + tokl)*64 + nt*16 + r16];
        float e = __expf(0.125f*S[nt][r] + bias);
        rs[r] += e;
        scw[tokl*72 + nt*16 + r16] = f2bf(e);
      }
    #pragma unroll
    for (int m = 1; m <= 8; m <<= 1)
      #pragma unroll
      for (int r = 0; r < 4; r++) rs[r] += __shfl_xor(rs[r], m);
    f32x4 O[4];
    #pragma unroll
    for (int nt = 0; nt < 4; nt++) O[nt] = (f32x4){0.f,0.f,0.f,0.f};
    #pragma unroll
    for (int ks = 0; ks < 2; ks++) {
      bf16x8 ap2 = *(const bf16x8*)&scw[r16*72 + ks*32 + q4*8];
      #pragma unroll
      for (int nt = 0; nt < 4; nt++) {
        bf16x8 bv = *(const bf16x8*)&avs[(nt*16 + r16)*72 + ks*32 + q4*8];
        O[nt] = __builtin_amdgcn_mfma_f32_16x16x32_bf16(ap2, bv, O[nt], 0,0,0);
      }
    }
    float inv[4];
    #pragma unroll
    for (int r = 0; r < 4; r++) inv[r] = 1.0f / rs[r];
    #pragma unroll
    for (int nt = 0; nt < 4; nt++)
      #pragma unroll
      for (int r = 0; r < 4; r++)
        aout[((size_t)b*3136 + tok0 + q4*4 + r)*512 + h*64 + nt*16 + r16] = f2bf(O[nt][r]*inv[r]);
  }
}

// ---------------- depthwise 3x3 conv on v + residual add (in place) ----------------
__global__ __launch_bounds__(256) void dwc_add(
    const u16* __restrict__ vb, const float* __restrict__ w_dwc,
    const float* __restrict__ b_dwc, u16* __restrict__ io)
{
  size_t idx = (size_t)blockIdx.x*256 + threadIdx.x;   // 16*3136*512
  int c = (int)(idx & 511);
  size_t bn = idx >> 9;
  int n = (int)(bn % 3136);
  int b = (int)(bn / 3136);
  int y = n / 56, x = n % 56;
  float acc = bf2f(io[idx]) + b_dwc[c];
  const float* wc = w_dwc + c*9;
  const u16* vbase = vb + (size_t)b*3136*512 + c;
  #pragma unroll
  for (int dy = 0; dy < 3; dy++) {
    int yy = y + dy - 1;
    if (yy < 0 || yy > 55) continue;
    #pragma unroll
    for (int dx = 0; dx < 3; dx++) {
      int xx = x + dx - 1;
      if (xx < 0 || xx > 55) continue;
      acc += bf2f(vbase[(size_t)(yy*56 + xx) << 9]) * wc[dy*3 + dx];
    }
  }
  io[idx] = f2bf(acc);
}

extern "C" void kernel_launch(void* const* d_in, const int* in_sizes, int n_in,
                              void* d_out, int out_size, void* d_ws, size_t ws_size,
                              hipStream_t stream)
{
  const float* x       = (const float*)d_in[0];
  const float* w_qkv   = (const float*)d_in[1];
  const float* w_proj  = (const float*)d_in[2];
  const float* b_proj  = (const float*)d_in[3];
  const float* w_dwc   = (const float*)d_in[4];
  const float* b_dwc   = (const float*)d_in[5];
  const float* an_bias = (const float*)d_in[6];
  const float* na_bias = (const float*)d_in[7];
  const float* ah_bias = (const float*)d_in[8];
  const float* aw_bias = (const float*)d_in[9];
  const float* ha_bias = (const float*)d_in[10];
  const float* wa_bias = (const float*)d_in[11];
  const float* ca_bias = (const float*)d_in[12];

  if (ws_size < 210000000u) return;

  char* p = (char*)d_ws;
  u16* regA   = (u16*)p;  p += 51380224;   // xb -> {PBIT,ABI,pav,psum,avTg}
  u16* qb     = (u16*)p;  p += 51380224;
  u16* kb     = (u16*)p;  p += 51380224;   // k -> attn_out (aout) after stage1
  u16* vb     = (u16*)p;  p += 51380224;
  u16* wqkvb  = (u16*)p;  p += 1572864;
  u16* wprojb = (u16*)p;  p += 524288;
  u16* agentb = (u16*)p;  p += 1048576;    // 16 x 64(padded) x 512 bf16
  float* PB   = (float*)p; p += 307456;
  float* AB   = (float*)p; p += 309248;

  // overlays in regA (live after qkv gemm, dead before stage2 writes aout->kb)
  float* PBIT = (float*)((char*)regA);                  // 6,422,528
  float* ABI  = (float*)((char*)regA + 6422528);        // 6,422,528
  float* pav  = (float*)((char*)regA + 12845056);       // 14,680,064
  float* psum = (float*)((char*)regA + 27525120);       //    229,376
  u16*   avTg = (u16*)  ((char*)regA + 27754496);       //  1,179,648
  u16*   aout = kb;

  cast_bf16<<<25088, 256, 0, stream>>>(x, regA, 6422528);
  cast_bf16<<<768,   256, 0, stream>>>(w_qkv, wqkvb, 196608);
  cast_bf16<<<256,   256, 0, stream>>>(w_proj, wprojb, 65536);

  gemm_bt<<<dim3(392,12), 256, 0, stream>>>(regA, wqkvb, 512, 0, qb, kb, vb, nullptr, nullptr);
  pool_q<<<2048, 256, 0, stream>>>(qb, agentb);
  bias_pre<<<602, 256, 0, stream>>>(an_bias, na_bias, ah_bias, aw_bias, ha_bias, wa_bias, ca_bias, PB, AB);
  pbit_expand<<<6272, 256, 0, stream>>>(PB, PBIT);
  abi_expand<<<6272, 256, 0, stream>>>(AB, ABI);
  stage1_mfma<<<dim3(128,7), 256, 0, stream>>>(kb, vb, agentb, PBIT, pav, psum);
  reduce_agv<<<2048, 256, 0, stream>>>(pav, psum, avTg);
  stage2_mfma<<<dim3(128,7), 256, 0, stream>>>(qb, agentb, avTg, ABI, aout);
  dwc_add<<<100352, 256, 0, stream>>>(vb, w_dwc, b_dwc, aout);
  gemm_bt<<<dim3(392,4), 256, 0, stream>>>(aout, wprojb, 512, 1, nullptr, nullptr, nullptr,
                                           (float*)d_out, b_proj);
}

// Round 4
// 554.152 us; speedup vs baseline: 4.6364x; 1.2275x over previous
//
#include <hip/hip_runtime.h>

typedef unsigned short u16;
typedef unsigned int   u32;
typedef unsigned long long u64;
typedef float  f32x4  __attribute__((ext_vector_type(4)));
typedef __bf16 bf16x8 __attribute__((ext_vector_type(8)));

#define DEV static __device__ __forceinline__

DEV float bf2f(u16 u){ union{float f;u32 i;}v; v.i=((u32)u)<<16; return v.f; }
DEV float bflo(u32 u){ union{float f;u32 i;}v; v.i=u<<16; return v.f; }
DEV float bfhi(u32 u){ union{float f;u32 i;}v; v.i=u&0xffff0000u; return v.f; }
DEV u16   f2bf(float f){ union{float f;u32 i;}v; v.f=f; return (u16)((v.i + 0x7fffu + ((v.i>>16)&1u))>>16); }

DEV void async16(const void* g, void* l){
  __builtin_amdgcn_global_load_lds((const __attribute__((address_space(1))) void*)g,
                                   (__attribute__((address_space(3))) void*)l, 16, 0, 0);
}

// ---------------- cast fp32 -> bf16 (4 elems/thread) ----------------
__global__ __launch_bounds__(256) void cast_bf16(const float* __restrict__ in,
                                                 u16* __restrict__ out, int n4)
{
  int i = blockIdx.x*256 + threadIdx.x;
  if (i >= n4) return;
  float4 v = ((const float4*)in)[i];
  ushort4 o;
  o.x = f2bf(v.x); o.y = f2bf(v.y); o.z = f2bf(v.z); o.w = f2bf(v.w);
  ((ushort4*)out)[i] = o;
}

// ---------------- bf16 MFMA GEMM, C[m][n] = sum_k A[m][k]*W[n][k] ----------------
__global__ __launch_bounds__(256) void gemm_bt(
    const u16* __restrict__ A, const u16* __restrict__ W, int K, int mode,
    u16* __restrict__ oq, u16* __restrict__ okk, u16* __restrict__ ov,
    float* __restrict__ of, const float* __restrict__ bias)
{
  __shared__ __align__(16) u16 As[4096];
  __shared__ __align__(16) u16 Bs[4096];
  const int tid  = threadIdx.x;
  const int wave = tid >> 6, lane = tid & 63;
  const int wm = wave >> 1, wn = wave & 1;
  const int r16 = lane & 15, q4 = lane >> 4;
  const size_t Abase = (size_t)blockIdx.x * 128 * K;
  const size_t Bbase = (size_t)blockIdx.y * 128 * K;

  f32x4 acc[4][4];
  #pragma unroll
  for (int i=0;i<4;i++)
    #pragma unroll
    for (int j=0;j<4;j++) acc[i][j] = (f32x4){0.f,0.f,0.f,0.f};

  for (int k0 = 0; k0 < K; k0 += 32) {
    #pragma unroll
    for (int i=0;i<2;i++){
      int c   = wave*128 + i*64 + lane;
      int row = c >> 2, kc = (c & 3) * 8;
      async16(A + Abase + (size_t)row*K + k0 + kc, (char*)As + (wave*128 + i*64)*16);
      async16(W + Bbase + (size_t)row*K + k0 + kc, (char*)Bs + (wave*128 + i*64)*16);
    }
    __syncthreads();
    bf16x8 af[4], bfr[4];
    #pragma unroll
    for (int i=0;i<4;i++) af[i]  = *(const bf16x8*)&As[(wm*64 + i*16 + r16)*32 + q4*8];
    #pragma unroll
    for (int j=0;j<4;j++) bfr[j] = *(const bf16x8*)&Bs[(wn*64 + j*16 + r16)*32 + q4*8];
    #pragma unroll
    for (int i=0;i<4;i++)
      #pragma unroll
      for (int j=0;j<4;j++)
        acc[i][j] = __builtin_amdgcn_mfma_f32_16x16x32_bf16(af[i], bfr[j], acc[i][j], 0,0,0);
    __syncthreads();
  }

  const int m0 = blockIdx.x*128 + wm*64;
  const int n0 = blockIdx.y*128 + wn*64;
  #pragma unroll
  for (int i=0;i<4;i++)
    #pragma unroll
    for (int j=0;j<4;j++)
      #pragma unroll
      for (int r=0;r<4;r++){
        int m = m0 + i*16 + q4*4 + r;
        int n = n0 + j*16 + r16;
        float val = acc[i][j][r];
        if (mode == 0){
          int sel = n >> 9, col = n & 511;
          u16* dst = sel==0 ? oq : (sel==1 ? okk : ov);
          dst[(size_t)m*512 + col] = f2bf(val);
        } else {
          of[(size_t)m*512 + n] = val + bias[n];
        }
      }
}

// ---------------- agent pooling: exact 8x8 block mean of q (64 padded slots) ----------------
__global__ __launch_bounds__(256) void pool_q(const u16* __restrict__ qb, u16* __restrict__ agentb)
{
  int idx = blockIdx.x*256 + threadIdx.x;          // 16*64*512
  int c = idx & 511;
  int ba = idx >> 9;
  int a = ba & 63, b = ba >> 6;
  if (a >= 49) { agentb[idx] = 0; return; }
  int ay = a / 7, ax = a % 7;
  const u16* base = qb + (size_t)b*3136*512 + c;
  float acc = 0.f;
  #pragma unroll
  for (int iy=0; iy<8; iy++){
    int rowoff = ((ay*8 + iy)*56 + ax*8) * 512;
    #pragma unroll
    for (int ix=0; ix<8; ix++) acc += bf2f(base[(size_t)rowoff + ix*512]);
  }
  agentb[idx] = f2bf(acc * 0.015625f);
}

// ---------------- bias tables: PB[8][49][196], AB[8][197][49] ----------------
DEV void lin1(float c, int S, int& i0, int& i1, float& w){
  if (c <= 0.f){ i0=0; i1=0; w=0.f; }
  else if (c >= (float)(S-1)){ i0=S-1; i1=S-1; w=0.f; }
  else { i0=(int)c; i1=i0+1; w=c-(float)i0; }
}
DEV float bilin7(const float* s, int Y, int X){
  int y0,y1,x0,x1; float wy,wx;
  lin1(0.5f*Y - 0.25f, 7, y0,y1,wy);
  lin1(0.5f*X - 0.25f, 7, x0,x1,wx);
  float v0 = s[y0*7+x0] + wx*(s[y0*7+x1]-s[y0*7+x0]);
  float v1 = s[y1*7+x0] + wx*(s[y1*7+x1]-s[y1*7+x0]);
  return v0 + wy*(v1 - v0);
}
__global__ __launch_bounds__(256) void bias_pre(
    const float* __restrict__ an_bias, const float* __restrict__ na_bias,
    const float* __restrict__ ah_bias, const float* __restrict__ aw_bias,
    const float* __restrict__ ha_bias, const float* __restrict__ wa_bias,
    const float* __restrict__ ca_bias, float* __restrict__ PB, float* __restrict__ AB)
{
  int idx = blockIdx.x*256 + threadIdx.x;
  if (idx < 8*49*196){
    int j = idx % 196; int ha = idx / 196; int a = ha % 49, h = ha / 49;
    int wy = j / 14, wx = j % 14;
    PB[idx] = bilin7(an_bias + (h*49+a)*49, wy, wx)
            + ah_bias[(h*49+a)*14 + wy] + aw_bias[(h*49+a)*14 + wx];
  }
  int idx2 = idx - 8*49*196;
  if (idx2 >= 0 && idx2 < 8*197*49){
    int a = idx2 % 49; int hr = idx2 / 49; int r = hr % 197, h = hr / 197;
    float v;
    if (r == 0) v = ca_bias[h*49 + a];
    else {
      int j = r - 1; int wy = j / 14, wx = j % 14;
      v = bilin7(na_bias + (h*49+a)*49, wy, wx)
        + ha_bias[(h*14+wy)*49 + a] + wa_bias[(h*14+wx)*49 + a];
    }
    AB[idx2] = v;
  }
}

// ---------------- PBIT[h][n][64]: stage-1 bias, interp 196->3136; pad agents = -1e30 ----------------
__global__ __launch_bounds__(256) void pbit_expand(const float* __restrict__ PB, float* __restrict__ PBIT)
{
  int idx = blockIdx.x*256 + threadIdx.x;   // 8*3136*64
  if (idx >= 1605632) return;
  int a = idx & 63; int t = idx >> 6; int n = t % 3136; int h = t / 3136;
  float val = -1e30f;
  if (a < 49) {
    const float* row = PB + (h*49 + a)*196;
    float c1 = (n + 0.5f)*0.0625f - 0.5f;
    if (c1 <= 0.f) val = row[0];
    else if (c1 >= 195.f) val = row[195];
    else { int j0 = (int)c1; float w = c1 - (float)j0; val = row[j0] + w*(row[j0+1]-row[j0]); }
  }
  PBIT[idx] = val;
}

// ---------------- ABI[h][n][64]: stage-2 bias, interp 197->3136; pad agents = -1e30 ----------------
__global__ __launch_bounds__(256) void abi_expand(const float* __restrict__ AB, float* __restrict__ ABI)
{
  int idx = blockIdx.x*256 + threadIdx.x;   // 8*3136*64
  if (idx >= 1605632) return;
  int a = idx & 63; int t = idx >> 6; int n = t % 3136; int h = t / 3136;
  float val = -1e30f;
  if (a < 49) {
    float c2 = (n + 0.5f)*(197.0f/3136.0f) - 0.5f;
    int r0; float w;
    if (c2 <= 0.f) { r0 = 0; w = 0.f; }
    else if (c2 >= 196.f) { r0 = 196; w = 0.f; }
    else { r0 = (int)c2; w = c2 - (float)r0; }
    int r1 = (r0 < 196) ? r0 + 1 : 196;
    float v0 = AB[(h*197 + r0)*49 + a];
    float v1 = AB[(h*197 + r1)*49 + a];
    val = v0 + w*(v1 - v0);
  }
  ABI[idx] = val;
}

// ---------------- stage 1 (MFMA): S^T = K·ah^T, exp->P (LDS), O += P·V per wave-owned agents ----
__global__ __launch_bounds__(256) void stage1_mfma(
    const u16* __restrict__ kb, const u16* __restrict__ vb,
    const u16* __restrict__ agentb, const float* __restrict__ PBIT,
    float* __restrict__ pav, float* __restrict__ psum)
{
  int bh = blockIdx.x, chunk = blockIdx.y;
  int b = bh >> 3, h = bh & 7;
  int tid = threadIdx.x, lane = tid & 63, w = tid >> 6;
  int r16 = lane & 15, q4 = lane >> 4;
  __shared__ __align__(16) u16 kld[64*64];   // XOR-swizzled chunks
  __shared__ __align__(16) u16 vt[64*68];    // v transposed [dim][token], stride 68
  __shared__ __align__(16) u16 scb[64*72];   // P [agent][token], stride 72

  int agent = w*16 + r16;
  bf16x8 bah[2];
  {
    const u16* ap = agentb + ((size_t)(b*64 + agent))*512 + h*64 + q4*8;
    bah[0] = *(const bf16x8*)ap;
    bah[1] = *(const bf16x8*)(ap + 32);
  }
  f32x4 Oacc[4];
  #pragma unroll
  for (int nt = 0; nt < 4; nt++) Oacc[nt] = (f32x4){0.f,0.f,0.f,0.f};
  float ssum = 0.f;
  int n0 = chunk * 448;
  const u16* kbase = kb + ((size_t)b*3136)*512 + h*64;
  const u16* vbase = vb + ((size_t)b*3136)*512 + h*64;

  for (int it = 0; it < 7; it++) {
    int nt0 = n0 + it*64;
    __syncthreads();
    #pragma unroll
    for (int i = 0; i < 2; i++) {
      int L = w*128 + i*64 + lane;
      int row = L >> 3, colc = (L & 7) ^ (row & 7);
      async16(kbase + (size_t)(nt0 + row)*512 + colc*8, (char*)kld + (w*128 + i*64)*16);
    }
    uint4 va[2]; int vtok[2], vdc[2];
    #pragma unroll
    for (int i = 0; i < 2; i++) {
      int c = tid + i*256;
      vtok[i] = c >> 3; vdc[i] = (c & 7)*8;
      va[i] = *(const uint4*)(vbase + (size_t)(nt0 + vtok[i])*512 + vdc[i]);
    }
    #pragma unroll
    for (int i = 0; i < 2; i++) {
      u32 uu[4] = {va[i].x, va[i].y, va[i].z, va[i].w};
      #pragma unroll
      for (int e = 0; e < 4; e++) {
        vt[(vdc[i] + 2*e + 0)*68 + vtok[i]] = (u16)(uu[e] & 0xffffu);
        vt[(vdc[i] + 2*e + 1)*68 + vtok[i]] = (u16)(uu[e] >> 16);
      }
    }
    __syncthreads();
    f32x4 S[4];
    #pragma unroll
    for (int mt = 0; mt < 4; mt++) S[mt] = (f32x4){0.f,0.f,0.f,0.f};
    #pragma unroll
    for (int ks = 0; ks < 2; ks++)
      #pragma unroll
      for (int mt = 0; mt < 4; mt++) {
        int row = mt*16 + r16;
        int colc = (ks*4 + q4) ^ (row & 7);
        bf16x8 afr = *(const bf16x8*)&kld[row*64 + colc*8];
        S[mt] = __builtin_amdgcn_mfma_f32_16x16x32_bf16(afr, bah[ks], S[mt], 0,0,0);
      }
    #pragma unroll
    for (int mt = 0; mt < 4; mt++) {
      u64 pk = 0;
      #pragma unroll
      for (int r = 0; r < 4; r++) {
        int tokl = mt*16 + q4*4 + r;
        float bias = PBIT[((size_t)h*3136 + nt0 + tokl)*64 + agent];
        float e = __expf(0.125f*S[mt][r] + bias);
        ssum += e;
        pk |= ((u64)f2bf(e)) << (16*r);
      }
      *(u64*)&scb[agent*72 + mt*16 + q4*4] = pk;
    }
    #pragma unroll
    for (int ks = 0; ks < 2; ks++) {
      bf16x8 ap = *(const bf16x8*)&scb[agent*72 + ks*32 + q4*8];
      #pragma unroll
      for (int nt = 0; nt < 4; nt++) {
        union { bf16x8 v; uint2 u[2]; } bb;
        int dim = nt*16 + r16;
        bb.u[0] = *(const uint2*)&vt[dim*68 + ks*32 + q4*8];
        bb.u[1] = *(const uint2*)&vt[dim*68 + ks*32 + q4*8 + 4];
        Oacc[nt] = __builtin_amdgcn_mfma_f32_16x16x32_bf16(ap, bb.v, Oacc[nt], 0,0,0);
      }
    }
  }
  ssum += __shfl_xor(ssum, 16);
  ssum += __shfl_xor(ssum, 32);
  size_t pb = (size_t)chunk*128 + bh;
  #pragma unroll
  for (int nt = 0; nt < 4; nt++)
    #pragma unroll
    for (int r = 0; r < 4; r++)
      pav[(pb*64 + (w*16 + q4*4 + r))*64 + nt*16 + r16] = Oacc[nt][r];
  if (lane < 16) psum[pb*64 + w*16 + lane] = ssum;
}

// ---------------- reduce partials -> normalized agent_v, transposed bf16 avT[bh][dim][72] ----------
__global__ __launch_bounds__(256) void reduce_agv(
    const float* __restrict__ pav, const float* __restrict__ psum, u16* __restrict__ avTg)
{
  int idx = blockIdx.x*256 + threadIdx.x;   // 128*64*64
  int d = idx & 63, a = (idx >> 6) & 63, bh = idx >> 12;
  float val = 0.f;
  if (a < 49) {
    float acc = 0.f, s = 0.f;
    #pragma unroll
    for (int c = 0; c < 7; c++) {
      acc += pav[(((size_t)c*128 + bh)*64 + a)*64 + d];
      s   += psum[((size_t)c*128 + bh)*64 + a];
    }
    val = acc / s;
  }
  avTg[((size_t)bh*64 + d)*72 + a] = f2bf(val);
}

// ---------------- stage 2 (MFMA): S2 = Q·ah^T, exp->P2 (wave LDS), out = P2·AV ----------------
__global__ __launch_bounds__(256) void stage2_mfma(
    const u16* __restrict__ qb, const u16* __restrict__ agentb,
    const u16* __restrict__ avTg, const float* __restrict__ ABI,
    u16* __restrict__ aout)
{
  int bh = blockIdx.x, chunk = blockIdx.y;
  int b = bh >> 3, h = bh & 7;
  int tid = threadIdx.x, lane = tid & 63, w = tid >> 6;
  int r16 = lane & 15, q4 = lane >> 4;
  __shared__ __align__(16) u16 avs[64*72];
  __shared__ __align__(16) u16 scb2[4*16*72];

  const u16* avsrc = avTg + (size_t)bh*4608;
  #pragma unroll
  for (int rr = 0; rr < 3; rr++) {
    int c = rr*256 + w*64 + lane;
    if (c < 576) async16(avsrc + c*8, (char*)avs + ((size_t)rr*256 + w*64)*16);
  }
  bf16x8 bah[4][2];
  #pragma unroll
  for (int nt = 0; nt < 4; nt++) {
    const u16* ap = agentb + ((size_t)(b*64 + nt*16 + r16))*512 + h*64 + q4*8;
    bah[nt][0] = *(const bf16x8*)ap;
    bah[nt][1] = *(const bf16x8*)(ap + 32);
  }
  __syncthreads();

  u16* scw = scb2 + w*16*72;
  for (int t = 0; t < 7; t++) {
    int tok0 = (chunk*28 + w*7 + t)*16;
    bf16x8 aq[2];
    {
      const u16* qp = qb + ((size_t)b*3136 + tok0 + r16)*512 + h*64 + q4*8;
      aq[0] = *(const bf16x8*)qp;
      aq[1] = *(const bf16x8*)(qp + 32);
    }
    f32x4 S[4];
    #pragma unroll
    for (int nt = 0; nt < 4; nt++) S[nt] = (f32x4){0.f,0.f,0.f,0.f};
    #pragma unroll
    for (int ks = 0; ks < 2; ks++)
      #pragma unroll
      for (int nt = 0; nt < 4; nt++)
        S[nt] = __builtin_amdgcn_mfma_f32_16x16x32_bf16(aq[ks], bah[nt][ks], S[nt], 0,0,0);
    float rs[4] = {0.f,0.f,0.f,0.f};
    #pragma unroll
    for (int nt = 0; nt < 4; nt++)
      #pragma unroll
      for (int r = 0; r < 4; r++) {
        int tokl = q4*4 + r;
        float bias = ABI[((size_t)h*3136 + tok0 + tokl)*64 + nt*16 + r16];
        float e = __expf(0.125f*S[nt][r] + bias);
        rs[r] += e;
        scw[tokl*72 + nt*16 + r16] = f2bf(e);
      }
    #pragma unroll
    for (int m = 1; m <= 8; m <<= 1)
      #pragma unroll
      for (int r = 0; r < 4; r++) rs[r] += __shfl_xor(rs[r], m);
    f32x4 O[4];
    #pragma unroll
    for (int nt = 0; nt < 4; nt++) O[nt] = (f32x4){0.f,0.f,0.f,0.f};
    #pragma unroll
    for (int ks = 0; ks < 2; ks++) {
      bf16x8 ap2 = *(const bf16x8*)&scw[r16*72 + ks*32 + q4*8];
      #pragma unroll
      for (int nt = 0; nt < 4; nt++) {
        bf16x8 bv = *(const bf16x8*)&avs[(nt*16 + r16)*72 + ks*32 + q4*8];
        O[nt] = __builtin_amdgcn_mfma_f32_16x16x32_bf16(ap2, bv, O[nt], 0,0,0);
      }
    }
    float inv[4];
    #pragma unroll
    for (int r = 0; r < 4; r++) inv[r] = 1.0f / rs[r];
    #pragma unroll
    for (int nt = 0; nt < 4; nt++)
      #pragma unroll
      for (int r = 0; r < 4; r++)
        aout[((size_t)b*3136 + tok0 + q4*4 + r)*512 + h*64 + nt*16 + r16] = f2bf(O[nt][r]*inv[r]);
  }
}

// ---------------- depthwise 3x3 + residual: wave = token, lane = 8-channel group ----------------
// weights loop-invariant in registers; all taps coalesced dwordx4
__global__ __launch_bounds__(256) void dwc_add2(
    const u16* __restrict__ vb, const float* __restrict__ w_dwc,
    const float* __restrict__ b_dwc, u16* __restrict__ io)
{
  int wave = (blockIdx.x << 2) + (threadIdx.x >> 6);   // 3136 waves, 16 tokens each
  int lane = threadIdx.x & 63;
  int c0 = lane * 8;

  float wt[9][8];
  {
    float tmp[72];
    const float4* wp = (const float4*)(w_dwc + c0*9);
    #pragma unroll
    for (int i = 0; i < 18; i++) {
      float4 v4 = wp[i];
      tmp[4*i] = v4.x; tmp[4*i+1] = v4.y; tmp[4*i+2] = v4.z; tmp[4*i+3] = v4.w;
    }
    #pragma unroll
    for (int j = 0; j < 8; j++)
      #pragma unroll
      for (int tp = 0; tp < 9; tp++) wt[tp][j] = tmp[j*9 + tp];
  }
  float bias[8];
  {
    const float4* bp = (const float4*)(b_dwc + c0);
    float4 a4 = bp[0], b4 = bp[1];
    bias[0]=a4.x; bias[1]=a4.y; bias[2]=a4.z; bias[3]=a4.w;
    bias[4]=b4.x; bias[5]=b4.y; bias[6]=b4.z; bias[7]=b4.w;
  }

  int t0 = wave * 16;                  // 16-token runs never cross batch (3136 % 16 == 0)
  int b = t0 / 3136;
  int n0 = t0 - b*3136;
  const u16* vbase = vb + ((size_t)b*3136)*512 + c0;

  for (int ti = 0; ti < 16; ti++) {
    int n = n0 + ti;
    int y = n / 56, x = n - y*56;
    size_t toff = ((size_t)b*3136 + n)*512 + c0;
    float acc[8];
    {
      uint4 uo = *(const uint4*)(io + toff);
      u32 uu[4] = {uo.x, uo.y, uo.z, uo.w};
      #pragma unroll
      for (int e = 0; e < 4; e++) {
        acc[2*e+0] = bflo(uu[e]) + bias[2*e+0];
        acc[2*e+1] = bfhi(uu[e]) + bias[2*e+1];
      }
    }
    #pragma unroll
    for (int dy = 0; dy < 3; dy++) {
      int yy = y + dy - 1;
      if (yy < 0 || yy > 55) continue;           // wave-uniform branch
      #pragma unroll
      for (int dx = 0; dx < 3; dx++) {
        int xx = x + dx - 1;
        if (xx < 0 || xx > 55) continue;
        uint4 uv = *(const uint4*)(vbase + ((size_t)(yy*56 + xx) << 9));
        u32 uu[4] = {uv.x, uv.y, uv.z, uv.w};
        const float* wr = wt[dy*3 + dx];
        #pragma unroll
        for (int e = 0; e < 4; e++) {
          acc[2*e+0] += bflo(uu[e]) * wr[2*e+0];
          acc[2*e+1] += bfhi(uu[e]) * wr[2*e+1];
        }
      }
    }
    uint4 pk;
    pk.x = (u32)f2bf(acc[0]) | ((u32)f2bf(acc[1]) << 16);
    pk.y = (u32)f2bf(acc[2]) | ((u32)f2bf(acc[3]) << 16);
    pk.z = (u32)f2bf(acc[4]) | ((u32)f2bf(acc[5]) << 16);
    pk.w = (u32)f2bf(acc[6]) | ((u32)f2bf(acc[7]) << 16);
    *(uint4*)(io + toff) = pk;
  }
}

extern "C" void kernel_launch(void* const* d_in, const int* in_sizes, int n_in,
                              void* d_out, int out_size, void* d_ws, size_t ws_size,
                              hipStream_t stream)
{
  const float* x       = (const float*)d_in[0];
  const float* w_qkv   = (const float*)d_in[1];
  const float* w_proj  = (const float*)d_in[2];
  const float* b_proj  = (const float*)d_in[3];
  const float* w_dwc   = (const float*)d_in[4];
  const float* b_dwc   = (const float*)d_in[5];
  const float* an_bias = (const float*)d_in[6];
  const float* na_bias = (const float*)d_in[7];
  const float* ah_bias = (const float*)d_in[8];
  const float* aw_bias = (const float*)d_in[9];
  const float* ha_bias = (const float*)d_in[10];
  const float* wa_bias = (const float*)d_in[11];
  const float* ca_bias = (const float*)d_in[12];

  if (ws_size < 210000000u) return;

  char* p = (char*)d_ws;
  u16* regA   = (u16*)p;  p += 51380224;   // xb -> {PBIT,ABI,pav,psum,avTg}
  u16* qb     = (u16*)p;  p += 51380224;
  u16* kb     = (u16*)p;  p += 51380224;   // k -> attn_out (aout) after stage1
  u16* vb     = (u16*)p;  p += 51380224;
  u16* wqkvb  = (u16*)p;  p += 1572864;
  u16* wprojb = (u16*)p;  p += 524288;
  u16* agentb = (u16*)p;  p += 1048576;    // 16 x 64(padded) x 512 bf16
  float* PB   = (float*)p; p += 307456;
  float* AB   = (float*)p; p += 309248;

  float* PBIT = (float*)((char*)regA);                  // 6,422,528
  float* ABI  = (float*)((char*)regA + 6422528);        // 6,422,528
  float* pav  = (float*)((char*)regA + 12845056);       // 14,680,064
  float* psum = (float*)((char*)regA + 27525120);       //    229,376
  u16*   avTg = (u16*)  ((char*)regA + 27754496);       //  1,179,648
  u16*   aout = kb;

  cast_bf16<<<25088, 256, 0, stream>>>(x, regA, 6422528);
  cast_bf16<<<768,   256, 0, stream>>>(w_qkv, wqkvb, 196608);
  cast_bf16<<<256,   256, 0, stream>>>(w_proj, wprojb, 65536);

  gemm_bt<<<dim3(392,12), 256, 0, stream>>>(regA, wqkvb, 512, 0, qb, kb, vb, nullptr, nullptr);
  pool_q<<<2048, 256, 0, stream>>>(qb, agentb);
  bias_pre<<<602, 256, 0, stream>>>(an_bias, na_bias, ah_bias, aw_bias, ha_bias, wa_bias, ca_bias, PB, AB);
  pbit_expand<<<6272, 256, 0, stream>>>(PB, PBIT);
  abi_expand<<<6272, 256, 0, stream>>>(AB, ABI);
  stage1_mfma<<<dim3(128,7), 256, 0, stream>>>(kb, vb, agentb, PBIT, pav, psum);
  reduce_agv<<<2048, 256, 0, stream>>>(pav, psum, avTg);
  stage2_mfma<<<dim3(128,7), 256, 0, stream>>>(qb, agentb, avTg, ABI, aout);
  dwc_add2<<<784, 256, 0, stream>>>(vb, w_dwc, b_dwc, aout);
  gemm_bt<<<dim3(392,4), 256, 0, stream>>>(aout, wprojb, 512, 1, nullptr, nullptr, nullptr,
                                           (float*)d_out, b_proj);
}

// Round 5
// 547.282 us; speedup vs baseline: 4.6946x; 1.0126x over previous
//
#include <hip/hip_runtime.h>

typedef unsigned short u16;
typedef unsigned int   u32;
typedef unsigned long long u64;
typedef float  f32x4  __attribute__((ext_vector_type(4)));
typedef __bf16 bf16x8 __attribute__((ext_vector_type(8)));

#define DEV static __device__ __forceinline__

DEV float bf2f(u16 u){ union{float f;u32 i;}v; v.i=((u32)u)<<16; return v.f; }
DEV float bflo(u32 u){ union{float f;u32 i;}v; v.i=u<<16; return v.f; }
DEV float bfhi(u32 u){ union{float f;u32 i;}v; v.i=u&0xffff0000u; return v.f; }
DEV u16   f2bf(float f){ union{float f;u32 i;}v; v.f=f; return (u16)((v.i + 0x7fffu + ((v.i>>16)&1u))>>16); }

DEV void async16(const void* g, void* l){
  __builtin_amdgcn_global_load_lds((const __attribute__((address_space(1))) void*)g,
                                   (__attribute__((address_space(3))) void*)l, 16, 0, 0);
}

// ---------------- cast fp32 -> bf16 (4 elems/thread) ----------------
__global__ __launch_bounds__(256) void cast_bf16(const float* __restrict__ in,
                                                 u16* __restrict__ out, int n4)
{
  int i = blockIdx.x*256 + threadIdx.x;
  if (i >= n4) return;
  float4 v = ((const float4*)in)[i];
  ushort4 o;
  o.x = f2bf(v.x); o.y = f2bf(v.y); o.z = f2bf(v.z); o.w = f2bf(v.w);
  ((ushort4*)out)[i] = o;
}

// ---------------- bf16 MFMA GEMM, C[m][n] = sum_k A[m][k]*W[n][k] ----------------
// BK=64, XOR-swizzled LDS (2-way max conflicts), swapped-operand MFMA so each
// lane holds 4 consecutive n -> packed uint2 (mode0) / float4+bias (mode1) stores.
__global__ __launch_bounds__(256) void gemm_bt(
    const u16* __restrict__ A, const u16* __restrict__ W, int K, int mode,
    u16* __restrict__ oq, u16* __restrict__ okk, u16* __restrict__ ov,
    float* __restrict__ of, const float* __restrict__ bias)
{
  __shared__ __align__(16) u16 As[8192];   // 128 rows x 64 (8 chunks of 16B, swizzled)
  __shared__ __align__(16) u16 Bs[8192];
  const int tid  = threadIdx.x;
  const int wave = tid >> 6, lane = tid & 63;
  const int wm = wave >> 1, wn = wave & 1;
  const int r16 = lane & 15, q4 = lane >> 4;
  const int xr = r16 & 7;
  const size_t Abase = (size_t)blockIdx.x * 128 * K;
  const size_t Bbase = (size_t)blockIdx.y * 128 * K;

  f32x4 acc[4][4];
  #pragma unroll
  for (int i=0;i<4;i++)
    #pragma unroll
    for (int j=0;j<4;j++) acc[i][j] = (f32x4){0.f,0.f,0.f,0.f};

  for (int k0 = 0; k0 < K; k0 += 64) {
    #pragma unroll
    for (int i=0;i<4;i++){
      int s   = i*256 + tid;                 // chunk slot 0..1023; dst = uniform + lane*16
      int row = s >> 3;
      int c   = (s & 7) ^ (row & 7);         // inverse of read-side swizzle
      async16(A + Abase + (size_t)row*K + k0 + c*8, (char*)As + (size_t)s*16);
      async16(W + Bbase + (size_t)row*K + k0 + c*8, (char*)Bs + (size_t)s*16);
    }
    __syncthreads();
    #pragma unroll
    for (int ks=0; ks<2; ks++){
      const int xo = ((ks*4 + q4) ^ xr) * 8;
      bf16x8 af[4], bfr[4];
      #pragma unroll
      for (int i=0;i<4;i++) af[i]  = *(const bf16x8*)&As[(wm*64 + i*16 + r16)*64 + xo];
      #pragma unroll
      for (int j=0;j<4;j++) bfr[j] = *(const bf16x8*)&Bs[(wn*64 + j*16 + r16)*64 + xo];
      #pragma unroll
      for (int i=0;i<4;i++)
        #pragma unroll
        for (int j=0;j<4;j++)   // swapped operands: D col=token(r16), reg-axis = n
          acc[i][j] = __builtin_amdgcn_mfma_f32_16x16x32_bf16(bfr[j], af[i], acc[i][j], 0,0,0);
    }
    __syncthreads();
  }

  const int m0 = blockIdx.x*128 + wm*64;
  const int n0 = blockIdx.y*128 + wn*64;
  if (mode == 0){
    int sel = blockIdx.y >> 2;               // 128-n tiles never straddle q/k/v
    u16* dst = sel==0 ? oq : (sel==1 ? okk : ov);
    #pragma unroll
    for (int i=0;i<4;i++){
      int token = m0 + i*16 + r16;
      #pragma unroll
      for (int j=0;j<4;j++){
        int col = (n0 + j*16 + q4*4) & 511;
        uint2 pk;
        pk.x = (u32)f2bf(acc[i][j][0]) | ((u32)f2bf(acc[i][j][1]) << 16);
        pk.y = (u32)f2bf(acc[i][j][2]) | ((u32)f2bf(acc[i][j][3]) << 16);
        *(uint2*)&dst[(size_t)token*512 + col] = pk;
      }
    }
  } else {
    #pragma unroll
    for (int j=0;j<4;j++){
      int nbase = n0 + j*16 + q4*4;
      float4 b4 = *(const float4*)&bias[nbase];
      #pragma unroll
      for (int i=0;i<4;i++){
        int token = m0 + i*16 + r16;
        float4 o4 = { acc[i][j][0]+b4.x, acc[i][j][1]+b4.y,
                      acc[i][j][2]+b4.z, acc[i][j][3]+b4.w };
        *(float4*)&of[(size_t)token*512 + nbase] = o4;
      }
    }
  }
}

// ---------------- agent pooling: exact 8x8 block mean of q (64 padded slots) ----------------
__global__ __launch_bounds__(256) void pool_q(const u16* __restrict__ qb, u16* __restrict__ agentb)
{
  int idx = blockIdx.x*256 + threadIdx.x;          // 16*64*512
  int c = idx & 511;
  int ba = idx >> 9;
  int a = ba & 63, b = ba >> 6;
  if (a >= 49) { agentb[idx] = 0; return; }
  int ay = a / 7, ax = a % 7;
  const u16* base = qb + (size_t)b*3136*512 + c;
  float acc = 0.f;
  #pragma unroll
  for (int iy=0; iy<8; iy++){
    int rowoff = ((ay*8 + iy)*56 + ax*8) * 512;
    #pragma unroll
    for (int ix=0; ix<8; ix++) acc += bf2f(base[(size_t)rowoff + ix*512]);
  }
  agentb[idx] = f2bf(acc * 0.015625f);
}

// ---------------- bias tables: PB[8][49][196], AB[8][197][49] ----------------
DEV void lin1(float c, int S, int& i0, int& i1, float& w){
  if (c <= 0.f){ i0=0; i1=0; w=0.f; }
  else if (c >= (float)(S-1)){ i0=S-1; i1=S-1; w=0.f; }
  else { i0=(int)c; i1=i0+1; w=c-(float)i0; }
}
DEV float bilin7(const float* s, int Y, int X){
  int y0,y1,x0,x1; float wy,wx;
  lin1(0.5f*Y - 0.25f, 7, y0,y1,wy);
  lin1(0.5f*X - 0.25f, 7, x0,x1,wx);
  float v0 = s[y0*7+x0] + wx*(s[y0*7+x1]-s[y0*7+x0]);
  float v1 = s[y1*7+x0] + wx*(s[y1*7+x1]-s[y1*7+x0]);
  return v0 + wy*(v1 - v0);
}
__global__ __launch_bounds__(256) void bias_pre(
    const float* __restrict__ an_bias, const float* __restrict__ na_bias,
    const float* __restrict__ ah_bias, const float* __restrict__ aw_bias,
    const float* __restrict__ ha_bias, const float* __restrict__ wa_bias,
    const float* __restrict__ ca_bias, float* __restrict__ PB, float* __restrict__ AB)
{
  int idx = blockIdx.x*256 + threadIdx.x;
  if (idx < 8*49*196){
    int j = idx % 196; int ha = idx / 196; int a = ha % 49, h = ha / 49;
    int wy = j / 14, wx = j % 14;
    PB[idx] = bilin7(an_bias + (h*49+a)*49, wy, wx)
            + ah_bias[(h*49+a)*14 + wy] + aw_bias[(h*49+a)*14 + wx];
  }
  int idx2 = idx - 8*49*196;
  if (idx2 >= 0 && idx2 < 8*197*49){
    int a = idx2 % 49; int hr = idx2 / 49; int r = hr % 197, h = hr / 197;
    float v;
    if (r == 0) v = ca_bias[h*49 + a];
    else {
      int j = r - 1; int wy = j / 14, wx = j % 14;
      v = bilin7(na_bias + (h*49+a)*49, wy, wx)
        + ha_bias[(h*14+wy)*49 + a] + wa_bias[(h*14+wx)*49 + a];
    }
    AB[idx2] = v;
  }
}

// ---------------- merged bias expand: PBIT[h][n][64] and ABI[h][n][64] ----------------
__global__ __launch_bounds__(256) void bias_expand2(
    const float* __restrict__ PB, const float* __restrict__ AB,
    float* __restrict__ PBIT, float* __restrict__ ABI)
{
  int idx = blockIdx.x*256 + threadIdx.x;
  if (idx < 1605632) {
    int a = idx & 63; int t = idx >> 6; int n = t % 3136; int h = t / 3136;
    float val = -1e30f;
    if (a < 49) {
      const float* row = PB + (h*49 + a)*196;
      float c1 = (n + 0.5f)*0.0625f - 0.5f;
      if (c1 <= 0.f) val = row[0];
      else if (c1 >= 195.f) val = row[195];
      else { int j0 = (int)c1; float w = c1 - (float)j0; val = row[j0] + w*(row[j0+1]-row[j0]); }
    }
    PBIT[idx] = val;
  } else {
    int idx2 = idx - 1605632;
    if (idx2 >= 1605632) return;
    int a = idx2 & 63; int t = idx2 >> 6; int n = t % 3136; int h = t / 3136;
    float val = -1e30f;
    if (a < 49) {
      float c2 = (n + 0.5f)*(197.0f/3136.0f) - 0.5f;
      int r0; float w;
      if (c2 <= 0.f) { r0 = 0; w = 0.f; }
      else if (c2 >= 196.f) { r0 = 196; w = 0.f; }
      else { r0 = (int)c2; w = c2 - (float)r0; }
      int r1 = (r0 < 196) ? r0 + 1 : 196;
      float v0 = AB[(h*197 + r0)*49 + a];
      float v1 = AB[(h*197 + r1)*49 + a];
      val = v0 + w*(v1 - v0);
    }
    ABI[idx2] = val;
  }
}

// ---------------- stage 1 (MFMA): S^T = K·ah^T, exp->P (LDS), O += P·V per wave-owned agents ----
__global__ __launch_bounds__(256) void stage1_mfma(
    const u16* __restrict__ kb, const u16* __restrict__ vb,
    const u16* __restrict__ agentb, const float* __restrict__ PBIT,
    float* __restrict__ pav, float* __restrict__ psum)
{
  int bh = blockIdx.x, chunk = blockIdx.y;
  int b = bh >> 3, h = bh & 7;
  int tid = threadIdx.x, lane = tid & 63, w = tid >> 6;
  int r16 = lane & 15, q4 = lane >> 4;
  __shared__ __align__(16) u16 kld[64*64];   // XOR-swizzled chunks
  __shared__ __align__(16) u16 vt[64*68];    // v transposed [dim][token], stride 68
  __shared__ __align__(16) u16 scb[64*72];   // P [agent][token], stride 72

  int agent = w*16 + r16;
  bf16x8 bah[2];
  {
    const u16* ap = agentb + ((size_t)(b*64 + agent))*512 + h*64 + q4*8;
    bah[0] = *(const bf16x8*)ap;
    bah[1] = *(const bf16x8*)(ap + 32);
  }
  f32x4 Oacc[4];
  #pragma unroll
  for (int nt = 0; nt < 4; nt++) Oacc[nt] = (f32x4){0.f,0.f,0.f,0.f};
  float ssum = 0.f;
  int n0 = chunk * 448;
  const u16* kbase = kb + ((size_t)b*3136)*512 + h*64;
  const u16* vbase = vb + ((size_t)b*3136)*512 + h*64;

  for (int it = 0; it < 7; it++) {
    int nt0 = n0 + it*64;
    __syncthreads();
    #pragma unroll
    for (int i = 0; i < 2; i++) {
      int L = w*128 + i*64 + lane;
      int row = L >> 3, colc = (L & 7) ^ (row & 7);
      async16(kbase + (size_t)(nt0 + row)*512 + colc*8, (char*)kld + (w*128 + i*64)*16);
    }
    uint4 va[2]; int vtok[2], vdc[2];
    #pragma unroll
    for (int i = 0; i < 2; i++) {
      int c = tid + i*256;
      vtok[i] = c >> 3; vdc[i] = (c & 7)*8;
      va[i] = *(const uint4*)(vbase + (size_t)(nt0 + vtok[i])*512 + vdc[i]);
    }
    #pragma unroll
    for (int i = 0; i < 2; i++) {
      u32 uu[4] = {va[i].x, va[i].y, va[i].z, va[i].w};
      #pragma unroll
      for (int e = 0; e < 4; e++) {
        vt[(vdc[i] + 2*e + 0)*68 + vtok[i]] = (u16)(uu[e] & 0xffffu);
        vt[(vdc[i] + 2*e + 1)*68 + vtok[i]] = (u16)(uu[e] >> 16);
      }
    }
    __syncthreads();
    f32x4 S[4];
    #pragma unroll
    for (int mt = 0; mt < 4; mt++) S[mt] = (f32x4){0.f,0.f,0.f,0.f};
    #pragma unroll
    for (int ks = 0; ks < 2; ks++)
      #pragma unroll
      for (int mt = 0; mt < 4; mt++) {
        int row = mt*16 + r16;
        int colc = (ks*4 + q4) ^ (row & 7);
        bf16x8 afr = *(const bf16x8*)&kld[row*64 + colc*8];
        S[mt] = __builtin_amdgcn_mfma_f32_16x16x32_bf16(afr, bah[ks], S[mt], 0,0,0);
      }
    #pragma unroll
    for (int mt = 0; mt < 4; mt++) {
      u64 pk = 0;
      #pragma unroll
      for (int r = 0; r < 4; r++) {
        int tokl = mt*16 + q4*4 + r;
        float bias = PBIT[((size_t)h*3136 + nt0 + tokl)*64 + agent];
        float e = __expf(0.125f*S[mt][r] + bias);
        ssum += e;
        pk |= ((u64)f2bf(e)) << (16*r);
      }
      *(u64*)&scb[agent*72 + mt*16 + q4*4] = pk;
    }
    #pragma unroll
    for (int ks = 0; ks < 2; ks++) {
      bf16x8 ap = *(const bf16x8*)&scb[agent*72 + ks*32 + q4*8];
      #pragma unroll
      for (int nt = 0; nt < 4; nt++) {
        union { bf16x8 v; uint2 u[2]; } bb;
        int dim = nt*16 + r16;
        bb.u[0] = *(const uint2*)&vt[dim*68 + ks*32 + q4*8];
        bb.u[1] = *(const uint2*)&vt[dim*68 + ks*32 + q4*8 + 4];
        Oacc[nt] = __builtin_amdgcn_mfma_f32_16x16x32_bf16(ap, bb.v, Oacc[nt], 0,0,0);
      }
    }
  }
  ssum += __shfl_xor(ssum, 16);
  ssum += __shfl_xor(ssum, 32);
  size_t pb = (size_t)chunk*128 + bh;
  #pragma unroll
  for (int nt = 0; nt < 4; nt++)
    #pragma unroll
    for (int r = 0; r < 4; r++)
      pav[(pb*64 + (w*16 + q4*4 + r))*64 + nt*16 + r16] = Oacc[nt][r];
  if (lane < 16) psum[pb*64 + w*16 + lane] = ssum;
}

// ---------------- reduce partials -> normalized agent_v, transposed bf16 avT[bh][dim][72] ----------
__global__ __launch_bounds__(256) void reduce_agv(
    const float* __restrict__ pav, const float* __restrict__ psum, u16* __restrict__ avTg)
{
  int idx = blockIdx.x*256 + threadIdx.x;   // 128*64*64
  int d = idx & 63, a = (idx >> 6) & 63, bh = idx >> 12;
  float val = 0.f;
  if (a < 49) {
    float acc = 0.f, s = 0.f;
    #pragma unroll
    for (int c = 0; c < 7; c++) {
      acc += pav[(((size_t)c*128 + bh)*64 + a)*64 + d];
      s   += psum[((size_t)c*128 + bh)*64 + a];
    }
    val = acc / s;
  }
  avTg[((size_t)bh*64 + d)*72 + a] = f2bf(val);
}

// ---------------- stage 2 (MFMA): S2 = Q·ah^T, exp->P2 (wave LDS), out = P2·AV ----------------
__global__ __launch_bounds__(256) void stage2_mfma(
    const u16* __restrict__ qb, const u16* __restrict__ agentb,
    const u16* __restrict__ avTg, const float* __restrict__ ABI,
    u16* __restrict__ aout)
{
  int bh = blockIdx.x, chunk = blockIdx.y;
  int b = bh >> 3, h = bh & 7;
  int tid = threadIdx.x, lane = tid & 63, w = tid >> 6;
  int r16 = lane & 15, q4 = lane >> 4;
  __shared__ __align__(16) u16 avs[64*72];
  __shared__ __align__(16) u16 scb2[4*16*72];

  const u16* avsrc = avTg + (size_t)bh*4608;
  #pragma unroll
  for (int rr = 0; rr < 3; rr++) {
    int c = rr*256 + w*64 + lane;
    if (c < 576) async16(avsrc + c*8, (char*)avs + ((size_t)rr*256 + w*64)*16);
  }
  bf16x8 bah[4][2];
  #pragma unroll
  for (int nt = 0; nt < 4; nt++) {
    const u16* ap = agentb + ((size_t)(b*64 + nt*16 + r16))*512 + h*64 + q4*8;
    bah[nt][0] = *(const bf16x8*)ap;
    bah[nt][1] = *(const bf16x8*)(ap + 32);
  }
  __syncthreads();

  u16* scw = scb2 + w*16*72;
  for (int t = 0; t < 7; t++) {
    int tok0 = (chunk*28 + w*7 + t)*16;
    bf16x8 aq[2];
    {
      const u16* qp = qb + ((size_t)b*3136 + tok0 + r16)*512 + h*64 + q4*8;
      aq[0] = *(const bf16x8*)qp;
      aq[1] = *(const bf16x8*)(qp + 32);
    }
    f32x4 S[4];
    #pragma unroll
    for (int nt = 0; nt < 4; nt++) S[nt] = (f32x4){0.f,0.f,0.f,0.f};
    #pragma unroll
    for (int ks = 0; ks < 2; ks++)
      #pragma unroll
      for (int nt = 0; nt < 4; nt++)
        S[nt] = __builtin_amdgcn_mfma_f32_16x16x32_bf16(aq[ks], bah[nt][ks], S[nt], 0,0,0);
    float rs[4] = {0.f,0.f,0.f,0.f};
    #pragma unroll
    for (int nt = 0; nt < 4; nt++)
      #pragma unroll
      for (int r = 0; r < 4; r++) {
        int tokl = q4*4 + r;
        float bias = ABI[((size_t)h*3136 + tok0 + tokl)*64 + nt*16 + r16];
        float e = __expf(0.125f*S[nt][r] + bias);
        rs[r] += e;
        scw[tokl*72 + nt*16 + r16] = f2bf(e);
      }
    #pragma unroll
    for (int m = 1; m <= 8; m <<= 1)
      #pragma unroll
      for (int r = 0; r < 4; r++) rs[r] += __shfl_xor(rs[r], m);
    f32x4 O[4];
    #pragma unroll
    for (int nt = 0; nt < 4; nt++) O[nt] = (f32x4){0.f,0.f,0.f,0.f};
    #pragma unroll
    for (int ks = 0; ks < 2; ks++) {
      bf16x8 ap2 = *(const bf16x8*)&scw[r16*72 + ks*32 + q4*8];
      #pragma unroll
      for (int nt = 0; nt < 4; nt++) {
        bf16x8 bv = *(const bf16x8*)&avs[(nt*16 + r16)*72 + ks*32 + q4*8];
        O[nt] = __builtin_amdgcn_mfma_f32_16x16x32_bf16(ap2, bv, O[nt], 0,0,0);
      }
    }
    float inv[4];
    #pragma unroll
    for (int r = 0; r < 4; r++) inv[r] = 1.0f / rs[r];
    #pragma unroll
    for (int nt = 0; nt < 4; nt++)
      #pragma unroll
      for (int r = 0; r < 4; r++)
        aout[((size_t)b*3136 + tok0 + q4*4 + r)*512 + h*64 + nt*16 + r16] = f2bf(O[nt][r]*inv[r]);
  }
}

// ---------------- depthwise 3x3 + residual: wave = token run, lane = 8-channel group ----------------
__global__ __launch_bounds__(256) void dwc_add2(
    const u16* __restrict__ vb, const float* __restrict__ w_dwc,
    const float* __restrict__ b_dwc, u16* __restrict__ io)
{
  int wave = (blockIdx.x << 2) + (threadIdx.x >> 6);   // 3136 waves, 16 tokens each
  int lane = threadIdx.x & 63;
  int c0 = lane * 8;

  float wt[9][8];
  {
    float tmp[72];
    const float4* wp = (const float4*)(w_dwc + c0*9);
    #pragma unroll
    for (int i = 0; i < 18; i++) {
      float4 v4 = wp[i];
      tmp[4*i] = v4.x; tmp[4*i+1] = v4.y; tmp[4*i+2] = v4.z; tmp[4*i+3] = v4.w;
    }
    #pragma unroll
    for (int j = 0; j < 8; j++)
      #pragma unroll
      for (int tp = 0; tp < 9; tp++) wt[tp][j] = tmp[j*9 + tp];
  }
  float bias[8];
  {
    const float4* bp = (const float4*)(b_dwc + c0);
    float4 a4 = bp[0], b4 = bp[1];
    bias[0]=a4.x; bias[1]=a4.y; bias[2]=a4.z; bias[3]=a4.w;
    bias[4]=b4.x; bias[5]=b4.y; bias[6]=b4.z; bias[7]=b4.w;
  }

  int t0 = wave * 16;
  int b = t0 / 3136;
  int n0 = t0 - b*3136;
  const u16* vbase = vb + ((size_t)b*3136)*512 + c0;

  for (int ti = 0; ti < 16; ti++) {
    int n = n0 + ti;
    int y = n / 56, x = n - y*56;
    size_t toff = ((size_t)b*3136 + n)*512 + c0;
    float acc[8];
    {
      uint4 uo = *(const uint4*)(io + toff);
      u32 uu[4] = {uo.x, uo.y, uo.z, uo.w};
      #pragma unroll
      for (int e = 0; e < 4; e++) {
        acc[2*e+0] = bflo(uu[e]) + bias[2*e+0];
        acc[2*e+1] = bfhi(uu[e]) + bias[2*e+1];
      }
    }
    #pragma unroll
    for (int dy = 0; dy < 3; dy++) {
      int yy = y + dy - 1;
      if (yy < 0 || yy > 55) continue;
      #pragma unroll
      for (int dx = 0; dx < 3; dx++) {
        int xx = x + dx - 1;
        if (xx < 0 || xx > 55) continue;
        uint4 uv = *(const uint4*)(vbase + ((size_t)(yy*56 + xx) << 9));
        u32 uu[4] = {uv.x, uv.y, uv.z, uv.w};
        const float* wr = wt[dy*3 + dx];
        #pragma unroll
        for (int e = 0; e < 4; e++) {
          acc[2*e+0] += bflo(uu[e]) * wr[2*e+0];
          acc[2*e+1] += bfhi(uu[e]) * wr[2*e+1];
        }
      }
    }
    uint4 pk;
    pk.x = (u32)f2bf(acc[0]) | ((u32)f2bf(acc[1]) << 16);
    pk.y = (u32)f2bf(acc[2]) | ((u32)f2bf(acc[3]) << 16);
    pk.z = (u32)f2bf(acc[4]) | ((u32)f2bf(acc[5]) << 16);
    pk.w = (u32)f2bf(acc[6]) | ((u32)f2bf(acc[7]) << 16);
    *(uint4*)(io + toff) = pk;
  }
}

extern "C" void kernel_launch(void* const* d_in, const int* in_sizes, int n_in,
                              void* d_out, int out_size, void* d_ws, size_t ws_size,
                              hipStream_t stream)
{
  const float* x       = (const float*)d_in[0];
  const float* w_qkv   = (const float*)d_in[1];
  const float* w_proj  = (const float*)d_in[2];
  const float* b_proj  = (const float*)d_in[3];
  const float* w_dwc   = (const float*)d_in[4];
  const float* b_dwc   = (const float*)d_in[5];
  const float* an_bias = (const float*)d_in[6];
  const float* na_bias = (const float*)d_in[7];
  const float* ah_bias = (const float*)d_in[8];
  const float* aw_bias = (const float*)d_in[9];
  const float* ha_bias = (const float*)d_in[10];
  const float* wa_bias = (const float*)d_in[11];
  const float* ca_bias = (const float*)d_in[12];

  if (ws_size < 210000000u) return;

  char* p = (char*)d_ws;
  u16* regA   = (u16*)p;  p += 51380224;   // xb -> {PBIT,ABI,pav,psum,avTg}
  u16* qb     = (u16*)p;  p += 51380224;
  u16* kb     = (u16*)p;  p += 51380224;   // k -> attn_out (aout) after stage1
  u16* vb     = (u16*)p;  p += 51380224;
  u16* wqkvb  = (u16*)p;  p += 1572864;
  u16* wprojb = (u16*)p;  p += 524288;
  u16* agentb = (u16*)p;  p += 1048576;    // 16 x 64(padded) x 512 bf16
  float* PB   = (float*)p; p += 307456;
  float* AB   = (float*)p; p += 309248;

  float* PBIT = (float*)((char*)regA);                  // 6,422,528
  float* ABI  = (float*)((char*)regA + 6422528);        // 6,422,528
  float* pav  = (float*)((char*)regA + 12845056);       // 14,680,064
  float* psum = (float*)((char*)regA + 27525120);       //    229,376
  u16*   avTg = (u16*)  ((char*)regA + 27754496);       //  1,179,648
  u16*   aout = kb;

  cast_bf16<<<25088, 256, 0, stream>>>(x, regA, 6422528);
  cast_bf16<<<768,   256, 0, stream>>>(w_qkv, wqkvb, 196608);
  cast_bf16<<<256,   256, 0, stream>>>(w_proj, wprojb, 65536);

  gemm_bt<<<dim3(392,12), 256, 0, stream>>>(regA, wqkvb, 512, 0, qb, kb, vb, nullptr, nullptr);
  pool_q<<<2048, 256, 0, stream>>>(qb, agentb);
  bias_pre<<<602, 256, 0, stream>>>(an_bias, na_bias, ah_bias, aw_bias, ha_bias, wa_bias, ca_bias, PB, AB);
  bias_expand2<<<12544, 256, 0, stream>>>(PB, AB, PBIT, ABI);
  stage1_mfma<<<dim3(128,7), 256, 0, stream>>>(kb, vb, agentb, PBIT, pav, psum);
  reduce_agv<<<2048, 256, 0, stream>>>(pav, psum, avTg);
  stage2_mfma<<<dim3(128,7), 256, 0, stream>>>(qb, agentb, avTg, ABI, aout);
  dwc_add2<<<784, 256, 0, stream>>>(vb, w_dwc, b_dwc, aout);
  gemm_bt<<<dim3(392,4), 256, 0, stream>>>(aout, wprojb, 512, 1, nullptr, nullptr, nullptr,
                                           (float*)d_out, b_proj);
}